// Round 5
// baseline (1054.628 us; speedup 1.0000x reference)
//
#include <hip/hip_runtime.h>
#include <hip/hip_bf16.h>

typedef unsigned short ushortT;
typedef short short8 __attribute__((ext_vector_type(8)));
typedef unsigned short ushort8v __attribute__((ext_vector_type(8)));
typedef float float4v __attribute__((ext_vector_type(4)));

// Problem constants (from reference)
constexpr int Nn   = 20000;
constexpr int Ee   = 320000;
constexpr int EP   = Ee + Nn;     // edges + self loops
constexpr float NSL = 0.2f;       // leaky_relu negative slope
constexpr int CAP  = 128;         // per-dst bucket capacity

// ---------- helpers ----------
__device__ __forceinline__ float b2f(__hip_bfloat16 v) { return __bfloat162float(v); }
__device__ __forceinline__ float bits2f(unsigned short u) {
    __hip_bfloat16 b; *(unsigned short*)&b = u; return __bfloat162float(b);
}
__device__ __forceinline__ unsigned short f2bits(float v) {
    __hip_bfloat16 b = __float2bfloat16(v); return *(unsigned short*)&b;
}
__device__ __forceinline__ float ldf(const void* p, size_t i, int bf) {
    return bf ? __bfloat162float(((const __hip_bfloat16*)p)[i])
              : ((const float*)p)[i];
}
__device__ __forceinline__ void stf(void* p, size_t i, float v, int bf) {
    if (bf) ((__hip_bfloat16*)p)[i] = __float2bfloat16(v);
    else    ((float*)p)[i] = v;
}

// ---------- parameter block ----------
struct MP {
    const void* x; const int* ei;
    const void* W1; const void* as1; const void* ad1; const void* b1;
    const void* W2; const void* as2; const void* ad2; const void* b2;
    const void* W3; const void* as3; const void* ad3; const void* b3;
    const void* Wm; const void* bm; const void* Wv; const void* bv;
    ushortT* aggn; ushortT* xb; ushortT* x1b; ushortT* h3;
    float* a1s; float* a1d; float* a2s; float* a2d; float* a3s; float* a3d;
    ushortT* WT1c; ushortT* WT2c; float* wp1; float* wp2;
    int* cnt; int* csr; int* eflag; int* fflag; int* bar;
    void* out;
};

// ---------- fast grid barrier (device-scope atomics + generation counter) ----------
// bar[0] = arrive count, bar[1] = generation. Pre-zeroed by hipMemsetAsync.
__device__ __forceinline__ void gbar(int* bar, int nblk) {
    __syncthreads();
    if (threadIdx.x == 0) {
        __threadfence();   // release all prior global writes to agent scope
        int g = __hip_atomic_load(bar + 1, __ATOMIC_RELAXED, __HIP_MEMORY_SCOPE_AGENT);
        int v = __hip_atomic_fetch_add(bar, 1, __ATOMIC_ACQ_REL, __HIP_MEMORY_SCOPE_AGENT);
        if (v == nblk - 1) {
            __hip_atomic_store(bar, 0, __ATOMIC_RELAXED, __HIP_MEMORY_SCOPE_AGENT);
            __hip_atomic_fetch_add(bar + 1, 1, __ATOMIC_RELEASE, __HIP_MEMORY_SCOPE_AGENT);
        } else {
            while (__hip_atomic_load(bar + 1, __ATOMIC_ACQUIRE, __HIP_MEMORY_SCOPE_AGENT) == g)
                __builtin_amdgcn_s_sleep(2);
        }
    }
    __syncthreads();
}

// ---------- phase 0: setup ----------
__device__ __forceinline__ int local_bf2(const unsigned* __restrict__ xbits, int* c_sh) {
    if (threadIdx.x == 0) *c_sh = 0;
    __syncthreads();
    int c = 0;
    for (int i = threadIdx.x; i < 512; i += 256) {
        unsigned e = (xbits[i] >> 7) & 0xFFu;
        if (e >= 110u && e <= 135u) ++c;
    }
    atomicAdd(c_sh, c);
    __syncthreads();
    int r = (*c_sh > 384) ? 1 : 0;
    __syncthreads();
    return r;
}

__device__ void setup_phase(const MP& p, int* sh_bad, int* sh_cs) {
    for (int vb = blockIdx.x; vb < 277; vb += gridDim.x) {
        if (vb < 79) {
            int gi = vb * 256 + threadIdx.x;
            if (gi < Nn) p.cnt[gi] = 0;
            if (vb == 0) {
                if (threadIdx.x == 0) *sh_bad = 0;
                __syncthreads();
                for (int i = threadIdx.x; i < 1024; i += 256)
                    if (p.ei[2 * i + 1] != 0) *sh_bad = 1;
                int bf = local_bf2((const unsigned*)p.x, sh_cs);
                if (threadIdx.x == 0) {
                    *p.eflag = (*sh_bad) ? 0 : 1;
                    *p.fflag = bf;
                }
                __syncthreads();
            }
        } else if (vb < 271) {
            int bf = local_bf2((const unsigned*)p.x, sh_cs);
            int idx = (vb - 79) * 256 + threadIdx.x;       // 0..49151
            if (idx < 64 * 512) {
                int jp = idx >> 9, r = idx & 511, hh = r >> 7, k = r & 127;
                p.WT1c[idx] = f2bits(ldf(p.W1, (size_t)k * 256 + hh * 64 + jp, bf));
            } else {
                int i2 = idx - 64 * 512;
                int jp = i2 >> 8, r = i2 & 255, hh = r >> 6, k = r & 63;
                p.WT2c[i2] = f2bits(ldf(p.W2, (size_t)k * 256 + hh * 64 + jp, bf));
            }
        } else {
            int bf = local_bf2((const unsigned*)p.x, sh_cs);
            int idx = (vb - 271) * 256 + threadIdx.x;      // 0..1535
            if (idx < 1024) {
                int sd = idx >> 9, r = idx & 511, hh = r >> 7, k = r & 127;
                const void* av = sd ? p.ad1 : p.as1;
                float acc = 0.f;
                for (int c = 0; c < 64; ++c)
                    acc = fmaf(ldf(p.W1, (size_t)k * 256 + hh * 64 + c, bf),
                               ldf(av, hh * 64 + c, bf), acc);
                p.wp1[idx] = acc;
            } else if (idx < 1536) {
                int i2 = idx - 1024;
                int sd = i2 >> 8, r = i2 & 255, hh = r >> 6, k = r & 63;
                const void* av = sd ? p.ad2 : p.as2;
                float acc = 0.f;
                for (int c = 0; c < 64; ++c)
                    acc = fmaf(ldf(p.W2, (size_t)k * 256 + hh * 64 + c, bf),
                               ldf(av, hh * 64 + c, bf), acc);
                p.wp2[i2] = acc;
            }
        }
    }
}

// ---------- phase 1: scatter + layer-1 alphas (independent, both need setup) ----------
__device__ void scat_alpha_phase(const MP& p) {
    const int gsz = gridDim.x * 256;
    const int sh = *p.eflag;
    for (int e = blockIdx.x * 256 + threadIdx.x; e < EP; e += gsz) {
        int si, di;
        if (e < Ee) {
            si = p.ei[(size_t)e << sh];
            di = p.ei[(size_t)(Ee + e) << sh];
        } else {
            si = di = e - Ee;
        }
        int pos = atomicAdd(p.cnt + di, 1);
        if (pos < CAP) p.csr[di * CAP + pos] = si;
    }
    const int bf = *p.fflag;
    const int cl = threadIdx.x & 31, g = threadIdx.x >> 5;
    const int c4 = cl * 4;
    for (int nb = blockIdx.x; nb < 2500; nb += gridDim.x) {
        const int n = nb * 8 + g;
        float xv[4];
        if (bf) {
            ushort4 u = *(const ushort4*)((const ushortT*)p.x + (size_t)n * 128 + c4);
            xv[0] = bits2f(u.x); xv[1] = bits2f(u.y); xv[2] = bits2f(u.z); xv[3] = bits2f(u.w);
            *(ushort4*)(p.xb + (size_t)n * 128 + c4) = u;
        } else {
            float4 f = *(const float4*)((const float*)p.x + (size_t)n * 128 + c4);
            xv[0] = f.x; xv[1] = f.y; xv[2] = f.z; xv[3] = f.w;
            ushort4 u;
            u.x = f2bits(f.x); u.y = f2bits(f.y); u.z = f2bits(f.z); u.w = f2bits(f.w);
            *(ushort4*)(p.xb + (size_t)n * 128 + c4) = u;
        }
        float pr[8];
#pragma unroll
        for (int j = 0; j < 8; ++j) {
            float4 wv = *(const float4*)(p.wp1 + j * 128 + c4);
            float t = 0.f;
            t = fmaf(xv[0], wv.x, t);
            t = fmaf(xv[1], wv.y, t);
            t = fmaf(xv[2], wv.z, t);
            t = fmaf(xv[3], wv.w, t);
            pr[j] = t;
        }
#pragma unroll
        for (int off = 1; off < 32; off <<= 1) {
#pragma unroll
            for (int j = 0; j < 8; ++j) pr[j] += __shfl_xor(pr[j], off, 32);
        }
        if (cl == 0) {
            *(float4*)(p.a1s + (size_t)n * 4) = make_float4(pr[0], pr[1], pr[2], pr[3]);
            *(float4*)(p.a1d + (size_t)n * 4) = make_float4(pr[4], pr[5], pr[6], pr[7]);
        }
    }
}

// ---------- per-edge eval helper ----------
__device__ __forceinline__ void edge_evals(const float* as_, int src, const float4& adv,
                                           float& s0, float& s1, float& s2, float& s3,
                                           float* slot) {
    float4 av = *(const float4*)(as_ + src * 4);
    float v0 = av.x + adv.x; v0 = v0 > 0.f ? v0 : NSL * v0; float e0 = __expf(v0);
    float v1 = av.y + adv.y; v1 = v1 > 0.f ? v1 : NSL * v1; float e1 = __expf(v1);
    float v2 = av.z + adv.z; v2 = v2 > 0.f ? v2 : NSL * v2; float e2 = __expf(v2);
    float v3 = av.w + adv.w; v3 = v3 > 0.f ? v3 : NSL * v3; float e3 = __expf(v3);
    s0 += e0; s1 += e1; s2 += e2; s3 += e3;
    *(float4*)slot = make_float4(e0, e1, e2, e3);
}

// ---------- phase 2: aggregate-first layer 1 (CIN=128) ----------
__device__ void aggx128_phase(const MP& p, char* pool) {
    const int lane = threadIdx.x & 63, seg = threadIdx.x >> 6;
    float* lal_s = (float*)pool + seg * (CAP * 4);
    for (int db = blockIdx.x; db < 5000; db += gridDim.x) {
        const int d = db * 4 + seg;
        const int deg = min(p.cnt[d], CAP);
        const int base = d * CAP;
        const float4 adv = *(const float4*)(p.a1d + d * 4);
        const int src0 = (lane < deg) ? p.csr[base + lane] : 0;
        const int src1 = (64 + lane < deg) ? p.csr[base + 64 + lane] : 0;
        float s0 = 0, s1 = 0, s2 = 0, s3 = 0;
        if (lane < deg)      edge_evals(p.a1s, src0, adv, s0, s1, s2, s3, lal_s + lane * 4);
        if (64 + lane < deg) edge_evals(p.a1s, src1, adv, s0, s1, s2, s3, lal_s + (64 + lane) * 4);
        const int q = lane >> 4, c8 = (lane & 15) * 8;
        float a[8] = {0, 0, 0, 0, 0, 0, 0, 0};
        auto do_edge = [&](int idx) {
            int sa = __shfl(src0, idx & 63, 64);
            int sb = __shfl(src1, idx & 63, 64);
            int src = (idx < 64) ? sa : sb;
            float ev = lal_s[idx * 4 + q];
            ushort8v xv = *(const ushort8v*)(p.xb + (size_t)src * 128 + c8);
#pragma unroll
            for (int j = 0; j < 8; ++j) a[j] = fmaf(ev, bits2f(xv[j]), a[j]);
        };
        int e = 0;
        for (; e + 4 <= deg; e += 4) {
            do_edge(e); do_edge(e + 1); do_edge(e + 2); do_edge(e + 3);
        }
        for (; e < deg; ++e) do_edge(e);
#pragma unroll
        for (int off = 1; off < 64; off <<= 1) {
            s0 += __shfl_xor(s0, off, 64);
            s1 += __shfl_xor(s1, off, 64);
            s2 += __shfl_xor(s2, off, 64);
            s3 += __shfl_xor(s3, off, 64);
        }
        const float sq = (q == 0) ? s0 : (q == 1) ? s1 : (q == 2) ? s2 : s3;
        const float iq = 0.25f / (sq + 1e-16f);
        ushort8v pk;
#pragma unroll
        for (int j = 0; j < 8; ++j) pk[j] = f2bits(a[j] * iq);
        *(ushort8v*)(p.aggn + (size_t)d * 512 + q * 128 + c8) = pk;
    }
}

// ---------- phase 4: aggregate-first layer 2 (CIN=64) ----------
__device__ void aggx64_phase(const MP& p, char* pool) {
    const int lane = threadIdx.x & 63, seg = threadIdx.x >> 6;
    float* lal_s = (float*)pool + seg * (CAP * 4);
    for (int db = blockIdx.x; db < 5000; db += gridDim.x) {
        const int d = db * 4 + seg;
        const int deg = min(p.cnt[d], CAP);
        const int base = d * CAP;
        const float4 adv = *(const float4*)(p.a2d + d * 4);
        const int src0 = (lane < deg) ? p.csr[base + lane] : 0;
        const int src1 = (64 + lane < deg) ? p.csr[base + 64 + lane] : 0;
        float s0 = 0, s1 = 0, s2 = 0, s3 = 0;
        if (lane < deg)      edge_evals(p.a2s, src0, adv, s0, s1, s2, s3, lal_s + lane * 4);
        if (64 + lane < deg) edge_evals(p.a2s, src1, adv, s0, s1, s2, s3, lal_s + (64 + lane) * 4);
        const int hl = lane >> 5, cl = lane & 31;
        const int q = cl >> 3, c8 = (cl & 7) * 8;
        float a[8] = {0, 0, 0, 0, 0, 0, 0, 0};
        auto do_edge = [&](int idx, bool valid) {
            int sa = __shfl(src0, idx & 63, 64);
            int sb = __shfl(src1, idx & 63, 64);
            int src = (idx < 64) ? sa : sb;
            float ev = valid ? lal_s[idx * 4 + q] : 0.0f;
            int off = valid ? src * 64 : 0;
            ushort8v xv = *(const ushort8v*)(p.x1b + (size_t)off + c8);
#pragma unroll
            for (int j = 0; j < 8; ++j) a[j] = fmaf(ev, bits2f(xv[j]), a[j]);
        };
        int e = 0;
        for (; e + 8 <= deg; e += 8) {
            do_edge(e + hl, true);
            do_edge(e + 2 + hl, true);
            do_edge(e + 4 + hl, true);
            do_edge(e + 6 + hl, true);
        }
        for (; e < deg; e += 2) do_edge(e + hl, (e + hl) < deg);
#pragma unroll
        for (int off = 1; off < 64; off <<= 1) {
            s0 += __shfl_xor(s0, off, 64);
            s1 += __shfl_xor(s1, off, 64);
            s2 += __shfl_xor(s2, off, 64);
            s3 += __shfl_xor(s3, off, 64);
        }
#pragma unroll
        for (int j = 0; j < 8; ++j) a[j] += __shfl_xor(a[j], 32, 64);
        const float sq = (q == 0) ? s0 : (q == 1) ? s1 : (q == 2) ? s2 : s3;
        const float iq = 0.25f / (sq + 1e-16f);
        if (hl == 0) {
            ushort8v pk;
#pragma unroll
            for (int j = 0; j < 8; ++j) pk[j] = f2bits(a[j] * iq);
            *(ushort8v*)(p.aggn + (size_t)d * 256 + q * 64 + c8) = pk;
        }
    }
}

// ---------- phase 3: layer-1 transform (MFMA) + fused layer-2 alphas ----------
__device__ void cat1_phase(const MP& p, char* pool) {
    constexpr int K = 512, KC = 128, SW = KC + 8, NCH = K / KC;
    ushortT* wt_s = (ushortT*)pool;                       // 17408 B
    ushortT* xs   = (ushortT*)(pool + 17408);             // 17408 B
    float*   wp_s = (float*)(pool + 34816);               // 2048 B
    const int bf = *p.fflag;
    const int lane = threadIdx.x & 63, w = threadIdx.x >> 6;
    const int ln = lane & 15, quad = lane >> 4;
    for (int bb = blockIdx.x; bb < 313; bb += gridDim.x) {
        const int base = bb * 64;
        float4v acc[4];
#pragma unroll
        for (int T = 0; T < 4; ++T) acc[T] = (float4v){0.f, 0.f, 0.f, 0.f};
        for (int i = threadIdx.x; i < 512; i += 256) wp_s[i] = p.wp2[i];
#pragma unroll
        for (int ch = 0; ch < NCH; ++ch) {
            for (int i = threadIdx.x; i < 64 * 16; i += 256) {
                int r = i >> 4, kc = (i & 15) * 8;
                *(short8*)(wt_s + r * SW + kc) =
                    *(const short8*)(p.WT1c + (size_t)r * K + ch * KC + kc);
                int node = base + r;
                short8 v = {0, 0, 0, 0, 0, 0, 0, 0};
                if (node < Nn) v = *(const short8*)(p.aggn + (size_t)node * K + ch * KC + kc);
                *(short8*)(xs + r * SW + kc) = v;
            }
            __syncthreads();
#pragma unroll
            for (int ks = 0; ks < 4; ++ks) {
                const int kb = ks * 32 + quad * 8;
                const short8 bfr = *(const short8*)(xs + (w * 16 + ln) * SW + kb);
#pragma unroll
                for (int T = 0; T < 4; ++T) {
                    const short8 afr = *(const short8*)(wt_s + (T * 16 + ln) * SW + kb);
                    acc[T] = __builtin_amdgcn_mfma_f32_16x16x32_bf16(afr, bfr, acc[T], 0, 0, 0);
                }
            }
            __syncthreads();
        }
        const int node = base + w * 16 + ln;
        const bool live = node < Nn;
        ushortT* on = p.x1b + (size_t)node * 64;
        float pr[8];
#pragma unroll
        for (int j = 0; j < 8; ++j) pr[j] = 0.f;
#pragma unroll
        for (int T = 0; T < 4; ++T) {
            const int jl = T * 16 + quad * 4;
            ushort4 pk;
            float t0 = fmaxf(acc[T][0] + ldf(p.b1, jl + 0, bf), 0.f);
            float t1 = fmaxf(acc[T][1] + ldf(p.b1, jl + 1, bf), 0.f);
            float t2 = fmaxf(acc[T][2] + ldf(p.b1, jl + 2, bf), 0.f);
            float t3 = fmaxf(acc[T][3] + ldf(p.b1, jl + 3, bf), 0.f);
            pk.x = f2bits(t0); pk.y = f2bits(t1); pk.z = f2bits(t2); pk.w = f2bits(t3);
            if (live) *(ushort4*)(on + jl) = pk;
#pragma unroll
            for (int j = 0; j < 8; ++j) {
                pr[j] = fmaf(t0, wp_s[j * 64 + jl + 0], pr[j]);
                pr[j] = fmaf(t1, wp_s[j * 64 + jl + 1], pr[j]);
                pr[j] = fmaf(t2, wp_s[j * 64 + jl + 2], pr[j]);
                pr[j] = fmaf(t3, wp_s[j * 64 + jl + 3], pr[j]);
            }
        }
#pragma unroll
        for (int j = 0; j < 8; ++j) {
            pr[j] += __shfl_xor(pr[j], 16, 64);
            pr[j] += __shfl_xor(pr[j], 32, 64);
        }
        if (quad == 0 && live) {
            *(float4*)(p.a2s + (size_t)node * 4) = make_float4(pr[0], pr[1], pr[2], pr[3]);
            *(float4*)(p.a2d + (size_t)node * 4) = make_float4(pr[4], pr[5], pr[6], pr[7]);
        }
        __syncthreads();
    }
}

// ---------- phase 5: layer-2 transform + layer-3 GEMM fused per tile (no barrier) ----------
__device__ void cat2s_phase(const MP& p, char* pool) {
    constexpr int K = 256, KC = 128, SW = KC + 8, NCH = K / KC, PAD = 36;
    ushortT* wt_s = (ushortT*)pool;                       // 17408 B (cat part)
    ushortT* xs   = (ushortT*)(pool + 17408);             // 17408 B (cat part)
    ushortT* x2t  = (ushortT*)pool;                       // 8192 B (reuse after MFMA)
    float*   xsh  = (float*)(pool + 8192);                // 9216 B
    const int bf = *p.fflag;
    const int lane = threadIdx.x & 63, w = threadIdx.x >> 6;
    const int ln = lane & 15, quad = lane >> 4;
    const int jc = threadIdx.x & 31, g = threadIdx.x >> 5;
    for (int bb = blockIdx.x; bb < 313; bb += gridDim.x) {
        const int base = bb * 64;
        float4v acc[4];
#pragma unroll
        for (int T = 0; T < 4; ++T) acc[T] = (float4v){0.f, 0.f, 0.f, 0.f};
#pragma unroll
        for (int ch = 0; ch < NCH; ++ch) {
            for (int i = threadIdx.x; i < 64 * 16; i += 256) {
                int r = i >> 4, kc = (i & 15) * 8;
                *(short8*)(wt_s + r * SW + kc) =
                    *(const short8*)(p.WT2c + (size_t)r * K + ch * KC + kc);
                int node = base + r;
                short8 v = {0, 0, 0, 0, 0, 0, 0, 0};
                if (node < Nn) v = *(const short8*)(p.aggn + (size_t)node * K + ch * KC + kc);
                *(short8*)(xs + r * SW + kc) = v;
            }
            __syncthreads();
#pragma unroll
            for (int ks = 0; ks < 4; ++ks) {
                const int kb = ks * 32 + quad * 8;
                const short8 bfr = *(const short8*)(xs + (w * 16 + ln) * SW + kb);
#pragma unroll
                for (int T = 0; T < 4; ++T) {
                    const short8 afr = *(const short8*)(wt_s + (T * 16 + ln) * SW + kb);
                    acc[T] = __builtin_amdgcn_mfma_f32_16x16x32_bf16(afr, bfr, acc[T], 0, 0, 0);
                }
            }
            __syncthreads();
        }
        // epilogue: x2 = relu(acc + b2) -> LDS tile (bf16, matches old global path)
#pragma unroll
        for (int T = 0; T < 4; ++T) {
            const int jl = T * 16 + quad * 4;
            ushort4 pk;
            pk.x = f2bits(fmaxf(acc[T][0] + ldf(p.b2, jl + 0, bf), 0.f));
            pk.y = f2bits(fmaxf(acc[T][1] + ldf(p.b2, jl + 1, bf), 0.f));
            pk.z = f2bits(fmaxf(acc[T][2] + ldf(p.b2, jl + 2, bf), 0.f));
            pk.w = f2bits(fmaxf(acc[T][3] + ldf(p.b2, jl + 3, bf), 0.f));
            *(ushort4*)(x2t + (w * 16 + ln) * 64 + jl) = pk;
        }
        __syncthreads();
        // layer-3 small GEMM on the tile (2 sub-blocks of 32 nodes)
        float avsr = ldf(p.as3, jc, bf), avdr = ldf(p.ad3, jc, bf);
#pragma unroll
        for (int sub = 0; sub < 2; ++sub) {
            for (int i = threadIdx.x; i < 32 * 64; i += 256) {
                int rr = i >> 6, kk = i & 63;
                xsh[kk * PAD + rr] = bits2f(x2t[(sub * 32 + rr) * 64 + kk]);
            }
            __syncthreads();
            float accs[4] = {};
            if (bf) {
                const __hip_bfloat16* Wb = (const __hip_bfloat16*)p.W3;
#pragma unroll 4
                for (int k = 0; k < 64; ++k) {
                    float4 xv = *(const float4*)(xsh + k * PAD + g * 4);
                    float wv = b2f(Wb[k * 32 + jc]);
                    accs[0] = fmaf(xv.x, wv, accs[0]);
                    accs[1] = fmaf(xv.y, wv, accs[1]);
                    accs[2] = fmaf(xv.z, wv, accs[2]);
                    accs[3] = fmaf(xv.w, wv, accs[3]);
                }
            } else {
                const float* Wf = (const float*)p.W3;
#pragma unroll 4
                for (int k = 0; k < 64; ++k) {
                    float4 xv = *(const float4*)(xsh + k * PAD + g * 4);
                    float wv = Wf[k * 32 + jc];
                    accs[0] = fmaf(xv.x, wv, accs[0]);
                    accs[1] = fmaf(xv.y, wv, accs[1]);
                    accs[2] = fmaf(xv.z, wv, accs[2]);
                    accs[3] = fmaf(xv.w, wv, accs[3]);
                }
            }
#pragma unroll
            for (int m = 0; m < 4; ++m) {
                int n = base + sub * 32 + g * 4 + m;
                if (n < Nn) {
                    p.h3[(size_t)n * 32 + jc] = f2bits(accs[m]);
                    float t1 = accs[m] * avsr;
                    float t2 = accs[m] * avdr;
#pragma unroll
                    for (int off = 16; off > 0; off >>= 1) {
                        t1 += __shfl_down(t1, off, 32);
                        t2 += __shfl_down(t2, off, 32);
                    }
                    if (jc == 0) { p.a3s[n] = t1; p.a3d[n] = t2; }
                }
            }
            __syncthreads();
        }
    }
}

// ---------- phase 6: layer-3 aggregation fused with output heads ----------
__device__ void aggr1f_phase(const MP& p, char* pool) {
    float* wm_s = (float*)pool;                           // 4096 B
    float* wv_s = (float*)(pool + 4096);                  // 4096 B
    float* lalp = (float*)(pool + 8192);                  // 4096 B
    int*   lofp = (int*)(pool + 12288);                   // 4096 B
    const int bf = *p.fflag;
    for (int i = threadIdx.x; i < 1024; i += 256) {
        wm_s[i] = ldf(p.Wm, i, bf);
        wv_s[i] = ldf(p.Wv, i, bf);
    }
    __syncthreads();
    const int c = threadIdx.x & 31, seg = threadIdx.x >> 5;
    float* lal = lalp + seg * CAP;
    int*   lof = lofp + seg * CAP;
    for (int bb = blockIdx.x; bb < 2500; bb += gridDim.x) {
        const int d = bb * 8 + seg;
        const int deg = min(p.cnt[d], CAP);
        const int base = d * CAP;
        const float advd = p.a3d[d];
        float s = 0;
        for (int i = c; i < deg; i += 32) {
            int src = p.csr[base + i];
            float v = p.a3s[src] + advd;
            v = v > 0.f ? v : NSL * v;
            float ev = __expf(v);
            s += ev;
            lal[i] = ev;
            lof[i] = src * 32;
        }
        float acc = 0.0f;
        int e = 0;
        for (; e + 4 <= deg; e += 4) {
            float ev0 = lal[e], ev1 = lal[e + 1];
            float ev2 = lal[e + 2], ev3 = lal[e + 3];
            int o0 = lof[e], o1 = lof[e + 1];
            int o2 = lof[e + 2], o3 = lof[e + 3];
            float h0 = bits2f(p.h3[o0 + c]), h1 = bits2f(p.h3[o1 + c]);
            float h2 = bits2f(p.h3[o2 + c]), h3v = bits2f(p.h3[o3 + c]);
            acc = fmaf(ev0, h0, acc);
            acc = fmaf(ev1, h1, acc);
            acc = fmaf(ev2, h2, acc);
            acc = fmaf(ev3, h3v, acc);
        }
        for (; e < deg; ++e) acc = fmaf(lal[e], bits2f(p.h3[lof[e] + c]), acc);
#pragma unroll
        for (int off = 1; off < 32; off <<= 1) s += __shfl_xor(s, off, 32);
        const float inv = 1.0f / (s + 1e-16f);
        const float z = inv * acc + ldf(p.b3, c, bf);
        stf(p.out, (size_t)2 * Nn * 32 + (size_t)d * 32 + c, z, bf);   // z
        float sm = ldf(p.bm, c, bf), sv = ldf(p.bv, c, bf);
#pragma unroll 8
        for (int k = 0; k < 32; ++k) {
            float zk = __shfl(z, k, 32);
            sm = fmaf(zk, wm_s[k * 32 + c], sm);
            sv = fmaf(zk, wv_s[k * 32 + c], sv);
        }
        float var = __expf(sv);
        var = fminf(fmaxf(var, 1e-8f), 100.0f);
        stf(p.out, (size_t)d * 32 + c, sm, bf);                        // z_mean
        stf(p.out, (size_t)Nn * 32 + (size_t)d * 32 + c, var, bf);     // z_var
    }
}

// ---------- single cooperative mega-kernel with custom fast barriers ----------
__global__ __launch_bounds__(256, 4) void mega_k(MP p, int nblk) {
    __shared__ __align__(16) char pool[36864];
    __shared__ int sh_bad, sh_cs;

    setup_phase(p, &sh_bad, &sh_cs);
    gbar(p.bar, nblk);
    scat_alpha_phase(p);
    gbar(p.bar, nblk);
    aggx128_phase(p, pool);
    gbar(p.bar, nblk);
    cat1_phase(p, pool);
    gbar(p.bar, nblk);
    aggx64_phase(p, pool);
    gbar(p.bar, nblk);
    cat2s_phase(p, pool);
    gbar(p.bar, nblk);
    aggr1f_phase(p, pool);
}

// ---------- fallback wrappers ----------
__global__ __launch_bounds__(256) void w_setup(MP p) {
    __shared__ int a, b; setup_phase(p, &a, &b);
}
__global__ __launch_bounds__(256) void w_scat_alpha(MP p) { scat_alpha_phase(p); }
__global__ __launch_bounds__(256) void w_aggx128(MP p) {
    __shared__ __align__(16) char pool[8192]; aggx128_phase(p, pool);
}
__global__ __launch_bounds__(256) void w_cat1(MP p) {
    __shared__ __align__(16) char pool[36864]; cat1_phase(p, pool);
}
__global__ __launch_bounds__(256) void w_aggx64(MP p) {
    __shared__ __align__(16) char pool[8192]; aggx64_phase(p, pool);
}
__global__ __launch_bounds__(256) void w_cat2s(MP p) {
    __shared__ __align__(16) char pool[36864]; cat2s_phase(p, pool);
}
__global__ __launch_bounds__(256) void w_aggr1f(MP p) {
    __shared__ __align__(16) char pool[16384]; aggr1f_phase(p, pool);
}

// ---------- launch ----------
extern "C" void kernel_launch(void* const* d_in, const int* in_sizes, int n_in,
                              void* d_out, int out_size, void* d_ws, size_t ws_size,
                              hipStream_t stream) {
    float* ws = (float*)d_ws;
    MP p;
    p.x   = d_in[0];  p.ei  = (const int*)d_in[1];
    p.W1  = d_in[2];  p.as1 = d_in[3];  p.ad1 = d_in[4];  p.b1 = d_in[5];
    p.W2  = d_in[6];  p.as2 = d_in[7];  p.ad2 = d_in[8];  p.b2 = d_in[9];
    p.W3  = d_in[10]; p.as3 = d_in[11]; p.ad3 = d_in[12]; p.b3 = d_in[13];
    p.Wm  = d_in[14]; p.bm  = d_in[15]; p.Wv  = d_in[16]; p.bv = d_in[17];
    p.aggn = (ushortT*)ws;                    // 20000*512 bf16
    p.xb   = (ushortT*)(ws + 5120000);        // 20000*128 bf16
    p.x1b  = (ushortT*)(ws + 6400000);        // 20000*64 bf16
    p.h3   = (ushortT*)(ws + 7040000);        // 20000*32 bf16
    p.a1s  = ws + 7360000;                    // 80,000
    p.a1d  = ws + 7440000;                    // 80,000
    p.a2s  = ws + 7520000;                    // 80,000
    p.a2d  = ws + 7600000;                    // 80,000
    p.a3s  = ws + 7680000;                    // 20,000
    p.a3d  = ws + 7700000;                    // 20,000
    p.WT1c = (ushortT*)(ws + 7720000);        // 64*512 bf16
    p.WT2c = (ushortT*)(ws + 7736384);        // 64*256 bf16
    p.wp1  = ws + 7744576;                    // 1,024
    p.wp2  = ws + 7745600;                    // 512
    p.cnt  = (int*)(ws + 7746112);            // 20,000
    p.csr  = (int*)(ws + 7766112);            // 2,560,000
    p.eflag = (int*)(ws + 10326112);
    p.fflag = (int*)(ws + 10326113);
    p.bar  = (int*)(ws + 10326114);           // 2 ints (8-byte aligned)
    p.out  = d_out;

    static int s_grid = 0;
    if (s_grid == 0) {
        int perCU = 0, ncu = 0;
        if (hipOccupancyMaxActiveBlocksPerMultiprocessor(&perCU, mega_k, 256, 0) != hipSuccess)
            perCU = 0;
        if (hipDeviceGetAttribute(&ncu, hipDeviceAttributeMultiprocessorCount, 0) != hipSuccess
            || ncu < 1)
            ncu = 256;
        s_grid = (perCU >= 1) ? perCU * ncu : -1;
        if (s_grid > 2048) s_grid = 2048;
        if (s_grid > 0 && s_grid < 64) s_grid = -1;
    }

    bool coop_ok = false;
    if (s_grid > 0) {
        hipError_t merr = hipMemsetAsync(p.bar, 0, 2 * sizeof(int), stream);
        if (merr == hipSuccess) {
            int nblk = s_grid;
            void* args[] = { (void*)&p, (void*)&nblk };
            hipError_t err = hipLaunchCooperativeKernel((const void*)mega_k,
                                                        dim3(s_grid), dim3(256),
                                                        args, 0, stream);
            coop_ok = (err == hipSuccess);
        }
    }
    if (!coop_ok) {
        w_setup<<<277, 256, 0, stream>>>(p);
        w_scat_alpha<<<2500, 256, 0, stream>>>(p);
        w_aggx128<<<5000, 256, 0, stream>>>(p);
        w_cat1<<<313, 256, 0, stream>>>(p);
        w_aggx64<<<5000, 256, 0, stream>>>(p);
        w_cat2s<<<313, 256, 0, stream>>>(p);
        w_aggr1f<<<2500, 256, 0, stream>>>(p);
    }
}

// Round 6
// 596.556 us; speedup vs baseline: 1.7679x; 1.7679x over previous
//
#include <hip/hip_runtime.h>
#include <hip/hip_bf16.h>

typedef unsigned short ushortT;
typedef short short8 __attribute__((ext_vector_type(8)));
typedef unsigned short ushort8v __attribute__((ext_vector_type(8)));
typedef float float4v __attribute__((ext_vector_type(4)));

// Problem constants (from reference)
constexpr int Nn   = 20000;
constexpr int Ee   = 320000;
constexpr int EP   = Ee + Nn;     // edges + self loops
constexpr float NSL = 0.2f;       // leaky_relu negative slope
constexpr int CAP  = 128;         // per-dst bucket capacity

// ---------- helpers ----------
__device__ __forceinline__ float b2f(__hip_bfloat16 v) { return __bfloat162float(v); }
__device__ __forceinline__ float bits2f(unsigned short u) {
    __hip_bfloat16 b; *(unsigned short*)&b = u; return __bfloat162float(b);
}
__device__ __forceinline__ unsigned short f2bits(float v) {
    __hip_bfloat16 b = __float2bfloat16(v); return *(unsigned short*)&b;
}
__device__ __forceinline__ float ldf(const void* p, size_t i, int bf) {
    return bf ? __bfloat162float(((const __hip_bfloat16*)p)[i])
              : ((const float*)p)[i];
}
__device__ __forceinline__ void stf(void* p, size_t i, float v, int bf) {
    if (bf) ((__hip_bfloat16*)p)[i] = __float2bfloat16(v);
    else    ((float*)p)[i] = v;
}

// ---------- parameter block ----------
struct MP {
    const void* x; const int* ei;
    const void* W1; const void* as1; const void* ad1; const void* b1;
    const void* W2; const void* as2; const void* ad2; const void* b2;
    const void* W3; const void* as3; const void* ad3; const void* b3;
    const void* Wm; const void* bm; const void* Wv; const void* bv;
    ushortT* aggn; ushortT* xb; ushortT* x1b; ushortT* h3;
    float* a1s; float* a1d; float* a2s; float* a2d; float* a3s; float* a3d;
    ushortT* WT1c; ushortT* WT2c; float* wp2;
    int* cnt; int* csr; int* eflag; int* fflag;
    void* out;
};

// ---------- K1: prep = flags(local) + scatter + W transposes + wp2 + alpha1 ----------
// grid MUST be exactly 2500 (alpha covers 2500*8 = 20000 nodes).
// wp1 (layer-1 alpha projection of W1) is recomputed per-block into LDS: removes the
// cross-block dependency that previously forced setup and alpha1 into separate
// dispatches. Total redundant cost ~2-7us device-wide; saves a ~15us dispatch.
__global__ __launch_bounds__(256) void prep_k(MP p) {
    __shared__ float wp1_s[1024];
    __shared__ int c_s, bad_s;
    if (threadIdx.x == 0) { c_s = 0; bad_s = 0; }
    __syncthreads();
    {
        const unsigned* xbits = (const unsigned*)p.x;
        int c = 0;
        for (int i = threadIdx.x; i < 512; i += 256) {
            unsigned e = (xbits[i] >> 7) & 0xFFu;
            if (e >= 110u && e <= 135u) ++c;
        }
        atomicAdd(&c_s, c);
        for (int i = threadIdx.x; i < 1024; i += 256)
            if (p.ei[2 * i + 1] != 0) bad_s = 1;     // benign multi-write of 1
    }
    __syncthreads();
    const int bf = (c_s > 384) ? 1 : 0;   // 1 => floats delivered as bf16
    const int sh = bad_s ? 0 : 1;         // 1 => int64 edge_index layout
    if (blockIdx.x == 0 && threadIdx.x == 0) { *p.eflag = sh; *p.fflag = bf; }

    // scatter slice (cnt pre-zeroed by hipMemsetAsync)
    for (int e = blockIdx.x * 256 + threadIdx.x; e < EP; e += gridDim.x * 256) {
        int si, di;
        if (e < Ee) {
            si = p.ei[(size_t)e << sh];
            di = p.ei[(size_t)(Ee + e) << sh];
        } else {
            si = di = e - Ee;   // self loop
        }
        int pos = atomicAdd(p.cnt + di, 1);
        if (pos < CAP) p.csr[di * CAP + pos] = si;
    }

    // weight transposes (blocks 0..191) / wp2 projection (block 192)
    if (blockIdx.x < 192) {
        int idx = blockIdx.x * 256 + threadIdx.x;    // < 49152
        if (idx < 32768) {
            int jp = idx >> 9, r = idx & 511, hh = r >> 7, k = r & 127;
            p.WT1c[idx] = f2bits(ldf(p.W1, (size_t)k * 256 + hh * 64 + jp, bf));
        } else {
            int i2 = idx - 32768;                    // < 16384
            int jp = i2 >> 8, r = i2 & 255, hh = r >> 6, k = r & 63;
            p.WT2c[i2] = f2bits(ldf(p.W2, (size_t)k * 256 + hh * 64 + jp, bf));
        }
    } else if (blockIdx.x == 192) {
        for (int i2 = threadIdx.x; i2 < 512; i2 += 256) {
            int sd = i2 >> 8, r = i2 & 255, hh = r >> 6, k = r & 63;
            const void* av = sd ? p.ad2 : p.as2;
            float acc = 0.f;
            for (int c = 0; c < 64; ++c)
                acc = fmaf(ldf(p.W2, (size_t)k * 256 + hh * 64 + c, bf),
                           ldf(av, hh * 64 + c, bf), acc);
            p.wp2[i2] = acc;
        }
    }

    // wp1 into LDS (every block; same formula/order as before -> bitwise identical)
    for (int t = threadIdx.x; t < 1024; t += 256) {
        int sd = t >> 9, hh = (t >> 7) & 3, k = t & 127;
        const void* av = sd ? p.ad1 : p.as1;
        float acc = 0.f;
        for (int c = 0; c < 64; ++c)
            acc = fmaf(ldf(p.W1, (size_t)k * 256 + hh * 64 + c, bf),
                       ldf(av, hh * 64 + c, bf), acc);
        wp1_s[t] = acc;
    }
    __syncthreads();

    // layer-1 alphas + x -> bf16 cast (8 nodes per block)
    const int cl = threadIdx.x & 31, g = threadIdx.x >> 5;
    const int n = blockIdx.x * 8 + g;                // grid 2500 exact -> n < 20000
    const int c4 = cl * 4;
    float xv[4];
    if (bf) {
        ushort4 u = *(const ushort4*)((const ushortT*)p.x + (size_t)n * 128 + c4);
        xv[0] = bits2f(u.x); xv[1] = bits2f(u.y); xv[2] = bits2f(u.z); xv[3] = bits2f(u.w);
        *(ushort4*)(p.xb + (size_t)n * 128 + c4) = u;
    } else {
        float4 f = *(const float4*)((const float*)p.x + (size_t)n * 128 + c4);
        xv[0] = f.x; xv[1] = f.y; xv[2] = f.z; xv[3] = f.w;
        ushort4 u;
        u.x = f2bits(f.x); u.y = f2bits(f.y); u.z = f2bits(f.z); u.w = f2bits(f.w);
        *(ushort4*)(p.xb + (size_t)n * 128 + c4) = u;
    }
    float pr[8];
#pragma unroll
    for (int j = 0; j < 8; ++j) {
        const float* wv = wp1_s + j * 128 + c4;
        float t = 0.f;
        t = fmaf(xv[0], wv[0], t);
        t = fmaf(xv[1], wv[1], t);
        t = fmaf(xv[2], wv[2], t);
        t = fmaf(xv[3], wv[3], t);
        pr[j] = t;
    }
#pragma unroll
    for (int off = 1; off < 32; off <<= 1) {
#pragma unroll
        for (int j = 0; j < 8; ++j) pr[j] += __shfl_xor(pr[j], off, 32);
    }
    if (cl == 0) {
        *(float4*)(p.a1s + (size_t)n * 4) = make_float4(pr[0], pr[1], pr[2], pr[3]);
        *(float4*)(p.a1d + (size_t)n * 4) = make_float4(pr[4], pr[5], pr[6], pr[7]);
    }
}

// ---------- per-edge eval helper ----------
__device__ __forceinline__ void edge_evals(const float* as_, int src, const float4& adv,
                                           float& s0, float& s1, float& s2, float& s3,
                                           float* slot) {
    float4 av = *(const float4*)(as_ + src * 4);
    float v0 = av.x + adv.x; v0 = v0 > 0.f ? v0 : NSL * v0; float e0 = __expf(v0);
    float v1 = av.y + adv.y; v1 = v1 > 0.f ? v1 : NSL * v1; float e1 = __expf(v1);
    float v2 = av.z + adv.z; v2 = v2 > 0.f ? v2 : NSL * v2; float e2 = __expf(v2);
    float v3 = av.w + adv.w; v3 = v3 > 0.f ? v3 : NSL * v3; float e3 = __expf(v3);
    s0 += e0; s1 += e1; s2 += e2; s3 += e3;
    *(float4*)slot = make_float4(e0, e1, e2, e3);
}

// ---------- K2: aggregate-first layer 1 (CIN=128); src offsets staged in LDS ----------
__global__ __launch_bounds__(256) void aggx128_k(MP p) {
    __shared__ float lal[4][CAP][4];
    __shared__ int   lsrc[4][CAP];
    const int lane = threadIdx.x & 63, seg = threadIdx.x >> 6;
    const int d = blockIdx.x * 4 + seg;              // 5000*4 = 20000 exact
    const int deg = min(p.cnt[d], CAP);
    const int base = d * CAP;
    const float4 adv = *(const float4*)(p.a1d + d * 4);
    const int src0 = (lane < deg) ? p.csr[base + lane] : 0;
    const int src1 = (64 + lane < deg) ? p.csr[base + 64 + lane] : 0;
    float s0 = 0, s1 = 0, s2 = 0, s3 = 0;
    if (lane < deg) {
        edge_evals(p.a1s, src0, adv, s0, s1, s2, s3, &lal[seg][lane][0]);
        lsrc[seg][lane] = src0 * 128;
    }
    if (64 + lane < deg) {
        edge_evals(p.a1s, src1, adv, s0, s1, s2, s3, &lal[seg][64 + lane][0]);
        lsrc[seg][64 + lane] = src1 * 128;
    }
    const int q = lane >> 4, c8 = (lane & 15) * 8;
    const float* lal_s = &lal[seg][0][0];
    const int* lsrc_s = &lsrc[seg][0];
    float a[8] = {0, 0, 0, 0, 0, 0, 0, 0};

    auto do_edge = [&](int idx) {
        float ev = lal_s[idx * 4 + q];               // broadcast (same addr all lanes in q-group)
        int sof = lsrc_s[idx];                       // broadcast
        ushort8v xv = *(const ushort8v*)(p.xb + (size_t)sof + c8);
#pragma unroll
        for (int j = 0; j < 8; ++j) a[j] = fmaf(ev, bits2f(xv[j]), a[j]);
    };

    int e = 0;
    for (; e + 4 <= deg; e += 4) {
        do_edge(e); do_edge(e + 1); do_edge(e + 2); do_edge(e + 3);
    }
    for (; e < deg; ++e) do_edge(e);

#pragma unroll
    for (int off = 1; off < 64; off <<= 1) {
        s0 += __shfl_xor(s0, off, 64);
        s1 += __shfl_xor(s1, off, 64);
        s2 += __shfl_xor(s2, off, 64);
        s3 += __shfl_xor(s3, off, 64);
    }
    const float sq = (q == 0) ? s0 : (q == 1) ? s1 : (q == 2) ? s2 : s3;
    const float iq = 0.25f / (sq + 1e-16f);
    ushort8v pk;
#pragma unroll
    for (int j = 0; j < 8; ++j) pk[j] = f2bits(a[j] * iq);
    *(ushort8v*)(p.aggn + (size_t)d * 512 + q * 128 + c8) = pk;
}

// ---------- K4: aggregate-first layer 2 (CIN=64); src offsets staged in LDS ----------
__global__ __launch_bounds__(256) void aggx64_k(MP p) {
    __shared__ float lal[4][CAP][4];
    __shared__ int   lsrc[4][CAP];
    const int lane = threadIdx.x & 63, seg = threadIdx.x >> 6;
    const int d = blockIdx.x * 4 + seg;
    const int deg = min(p.cnt[d], CAP);
    const int base = d * CAP;
    const float4 adv = *(const float4*)(p.a2d + d * 4);
    const int src0 = (lane < deg) ? p.csr[base + lane] : 0;
    const int src1 = (64 + lane < deg) ? p.csr[base + 64 + lane] : 0;
    float s0 = 0, s1 = 0, s2 = 0, s3 = 0;
    if (lane < deg) {
        edge_evals(p.a2s, src0, adv, s0, s1, s2, s3, &lal[seg][lane][0]);
        lsrc[seg][lane] = src0 * 64;
    }
    if (64 + lane < deg) {
        edge_evals(p.a2s, src1, adv, s0, s1, s2, s3, &lal[seg][64 + lane][0]);
        lsrc[seg][64 + lane] = src1 * 64;
    }
    const int hl = lane >> 5, cl = lane & 31;
    const int q = cl >> 3, c8 = (cl & 7) * 8;
    const float* lal_s = &lal[seg][0][0];
    const int* lsrc_s = &lsrc[seg][0];
    float a[8] = {0, 0, 0, 0, 0, 0, 0, 0};

    auto do_edge = [&](int idx, bool valid) {
        float ev = valid ? lal_s[idx * 4 + q] : 0.0f;
        int off = valid ? lsrc_s[idx] : 0;
        ushort8v xv = *(const ushort8v*)(p.x1b + (size_t)off + c8);
#pragma unroll
        for (int j = 0; j < 8; ++j) a[j] = fmaf(ev, bits2f(xv[j]), a[j]);
    };

    int e = 0;
    for (; e + 8 <= deg; e += 8) {
        do_edge(e + hl, true);
        do_edge(e + 2 + hl, true);
        do_edge(e + 4 + hl, true);
        do_edge(e + 6 + hl, true);
    }
    for (; e < deg; e += 2) do_edge(e + hl, (e + hl) < deg);

#pragma unroll
    for (int off = 1; off < 64; off <<= 1) {
        s0 += __shfl_xor(s0, off, 64);
        s1 += __shfl_xor(s1, off, 64);
        s2 += __shfl_xor(s2, off, 64);
        s3 += __shfl_xor(s3, off, 64);
    }
#pragma unroll
    for (int j = 0; j < 8; ++j) a[j] += __shfl_xor(a[j], 32, 64);
    const float sq = (q == 0) ? s0 : (q == 1) ? s1 : (q == 2) ? s2 : s3;
    const float iq = 0.25f / (sq + 1e-16f);
    if (hl == 0) {
        ushort8v pk;
#pragma unroll
        for (int j = 0; j < 8; ++j) pk[j] = f2bits(a[j] * iq);
        *(ushort8v*)(p.aggn + (size_t)d * 256 + q * 64 + c8) = pk;
    }
}

// ---------- K3: layer-1 transform (MFMA) + fused layer-2 alphas ----------
__global__ __launch_bounds__(256) void cat1_k(MP p) {
    constexpr int K = 512, KC = 128, SW = KC + 8, NCH = K / KC;
    __shared__ ushortT wt_s[64 * SW];
    __shared__ ushortT xs[64 * SW];
    __shared__ float wp_s[512];
    const int bf = *p.fflag;
    const int lane = threadIdx.x & 63, w = threadIdx.x >> 6;
    const int ln = lane & 15, quad = lane >> 4;
    const int base = blockIdx.x * 64;                // grid 313
    float4v acc[4];
#pragma unroll
    for (int T = 0; T < 4; ++T) acc[T] = (float4v){0.f, 0.f, 0.f, 0.f};
    for (int i = threadIdx.x; i < 512; i += 256) wp_s[i] = p.wp2[i];
#pragma unroll
    for (int ch = 0; ch < NCH; ++ch) {
        for (int i = threadIdx.x; i < 64 * 16; i += 256) {
            int r = i >> 4, kc = (i & 15) * 8;
            *(short8*)(wt_s + r * SW + kc) =
                *(const short8*)(p.WT1c + (size_t)r * K + ch * KC + kc);
            int node = base + r;
            short8 v = {0, 0, 0, 0, 0, 0, 0, 0};
            if (node < Nn) v = *(const short8*)(p.aggn + (size_t)node * K + ch * KC + kc);
            *(short8*)(xs + r * SW + kc) = v;
        }
        __syncthreads();
#pragma unroll
        for (int ks = 0; ks < 4; ++ks) {
            const int kb = ks * 32 + quad * 8;
            const short8 bfr = *(const short8*)(xs + (w * 16 + ln) * SW + kb);
#pragma unroll
            for (int T = 0; T < 4; ++T) {
                const short8 afr = *(const short8*)(wt_s + (T * 16 + ln) * SW + kb);
                acc[T] = __builtin_amdgcn_mfma_f32_16x16x32_bf16(afr, bfr, acc[T], 0, 0, 0);
            }
        }
        __syncthreads();
    }
    const int node = base + w * 16 + ln;
    const bool live = node < Nn;
    ushortT* on = p.x1b + (size_t)node * 64;
    float pr[8];
#pragma unroll
    for (int j = 0; j < 8; ++j) pr[j] = 0.f;
#pragma unroll
    for (int T = 0; T < 4; ++T) {
        const int jl = T * 16 + quad * 4;
        ushort4 pk;
        float t0 = fmaxf(acc[T][0] + ldf(p.b1, jl + 0, bf), 0.f);
        float t1 = fmaxf(acc[T][1] + ldf(p.b1, jl + 1, bf), 0.f);
        float t2 = fmaxf(acc[T][2] + ldf(p.b1, jl + 2, bf), 0.f);
        float t3 = fmaxf(acc[T][3] + ldf(p.b1, jl + 3, bf), 0.f);
        pk.x = f2bits(t0); pk.y = f2bits(t1); pk.z = f2bits(t2); pk.w = f2bits(t3);
        if (live) *(ushort4*)(on + jl) = pk;
#pragma unroll
        for (int j = 0; j < 8; ++j) {
            pr[j] = fmaf(t0, wp_s[j * 64 + jl + 0], pr[j]);
            pr[j] = fmaf(t1, wp_s[j * 64 + jl + 1], pr[j]);
            pr[j] = fmaf(t2, wp_s[j * 64 + jl + 2], pr[j]);
            pr[j] = fmaf(t3, wp_s[j * 64 + jl + 3], pr[j]);
        }
    }
#pragma unroll
    for (int j = 0; j < 8; ++j) {
        pr[j] += __shfl_xor(pr[j], 16, 64);
        pr[j] += __shfl_xor(pr[j], 32, 64);
    }
    if (quad == 0 && live) {
        *(float4*)(p.a2s + (size_t)node * 4) = make_float4(pr[0], pr[1], pr[2], pr[3]);
        *(float4*)(p.a2d + (size_t)node * 4) = make_float4(pr[4], pr[5], pr[6], pr[7]);
    }
}

// ---------- K5: layer-2 transform + layer-3 GEMM fused per tile ----------
__global__ __launch_bounds__(256) void cat2s_k(MP p) {
    constexpr int K = 256, KC = 128, SW = KC + 8, NCH = K / KC, PAD = 36;
    __shared__ __align__(16) char pool[36864];
    ushortT* wt_s = (ushortT*)pool;                       // 17408 B (MFMA part)
    ushortT* xs   = (ushortT*)(pool + 17408);             // 17408 B (MFMA part)
    ushortT* x2t  = (ushortT*)pool;                       // 8192 B (reuse after MFMA)
    float*   xsh  = (float*)(pool + 8192);                // 9216 B
    const int bf = *p.fflag;
    const int lane = threadIdx.x & 63, w = threadIdx.x >> 6;
    const int ln = lane & 15, quad = lane >> 4;
    const int jc = threadIdx.x & 31, g = threadIdx.x >> 5;
    const int base = blockIdx.x * 64;                // grid 313
    float4v acc[4];
#pragma unroll
    for (int T = 0; T < 4; ++T) acc[T] = (float4v){0.f, 0.f, 0.f, 0.f};
#pragma unroll
    for (int ch = 0; ch < NCH; ++ch) {
        for (int i = threadIdx.x; i < 64 * 16; i += 256) {
            int r = i >> 4, kc = (i & 15) * 8;
            *(short8*)(wt_s + r * SW + kc) =
                *(const short8*)(p.WT2c + (size_t)r * K + ch * KC + kc);
            int node = base + r;
            short8 v = {0, 0, 0, 0, 0, 0, 0, 0};
            if (node < Nn) v = *(const short8*)(p.aggn + (size_t)node * K + ch * KC + kc);
            *(short8*)(xs + r * SW + kc) = v;
        }
        __syncthreads();
#pragma unroll
        for (int ks = 0; ks < 4; ++ks) {
            const int kb = ks * 32 + quad * 8;
            const short8 bfr = *(const short8*)(xs + (w * 16 + ln) * SW + kb);
#pragma unroll
            for (int T = 0; T < 4; ++T) {
                const short8 afr = *(const short8*)(wt_s + (T * 16 + ln) * SW + kb);
                acc[T] = __builtin_amdgcn_mfma_f32_16x16x32_bf16(afr, bfr, acc[T], 0, 0, 0);
            }
        }
        __syncthreads();
    }
    // epilogue: x2 = relu(acc + b2) -> LDS tile
#pragma unroll
    for (int T = 0; T < 4; ++T) {
        const int jl = T * 16 + quad * 4;
        ushort4 pk;
        pk.x = f2bits(fmaxf(acc[T][0] + ldf(p.b2, jl + 0, bf), 0.f));
        pk.y = f2bits(fmaxf(acc[T][1] + ldf(p.b2, jl + 1, bf), 0.f));
        pk.z = f2bits(fmaxf(acc[T][2] + ldf(p.b2, jl + 2, bf), 0.f));
        pk.w = f2bits(fmaxf(acc[T][3] + ldf(p.b2, jl + 3, bf), 0.f));
        *(ushort4*)(x2t + (w * 16 + ln) * 64 + jl) = pk;
    }
    __syncthreads();
    // layer-3 small GEMM on the tile (2 sub-blocks of 32 nodes)
    float avsr = ldf(p.as3, jc, bf), avdr = ldf(p.ad3, jc, bf);
#pragma unroll
    for (int sub = 0; sub < 2; ++sub) {
        for (int i = threadIdx.x; i < 32 * 64; i += 256) {
            int rr = i >> 6, kk = i & 63;
            xsh[kk * PAD + rr] = bits2f(x2t[(sub * 32 + rr) * 64 + kk]);
        }
        __syncthreads();
        float accs[4] = {};
        if (bf) {
            const __hip_bfloat16* Wb = (const __hip_bfloat16*)p.W3;
#pragma unroll 4
            for (int k = 0; k < 64; ++k) {
                float4 xv = *(const float4*)(xsh + k * PAD + g * 4);
                float wv = b2f(Wb[k * 32 + jc]);
                accs[0] = fmaf(xv.x, wv, accs[0]);
                accs[1] = fmaf(xv.y, wv, accs[1]);
                accs[2] = fmaf(xv.z, wv, accs[2]);
                accs[3] = fmaf(xv.w, wv, accs[3]);
            }
        } else {
            const float* Wf = (const float*)p.W3;
#pragma unroll 4
            for (int k = 0; k < 64; ++k) {
                float4 xv = *(const float4*)(xsh + k * PAD + g * 4);
                float wv = Wf[k * 32 + jc];
                accs[0] = fmaf(xv.x, wv, accs[0]);
                accs[1] = fmaf(xv.y, wv, accs[1]);
                accs[2] = fmaf(xv.z, wv, accs[2]);
                accs[3] = fmaf(xv.w, wv, accs[3]);
            }
        }
#pragma unroll
        for (int m = 0; m < 4; ++m) {
            int n = base + sub * 32 + g * 4 + m;
            if (n < Nn) {
                p.h3[(size_t)n * 32 + jc] = f2bits(accs[m]);
                float t1 = accs[m] * avsr;
                float t2 = accs[m] * avdr;
#pragma unroll
                for (int off = 16; off > 0; off >>= 1) {
                    t1 += __shfl_down(t1, off, 32);
                    t2 += __shfl_down(t2, off, 32);
                }
                if (jc == 0) { p.a3s[n] = t1; p.a3d[n] = t2; }
            }
        }
        __syncthreads();
    }
}

// ---------- K6: layer-3 aggregation fused with output heads ----------
__global__ __launch_bounds__(256) void aggr1f_k(MP p) {
    __shared__ float wm_s[1024], wv_s[1024];
    __shared__ float lal[8][CAP];
    __shared__ int   lof[8][CAP];
    const int bf = *p.fflag;
    for (int i = threadIdx.x; i < 1024; i += 256) {
        wm_s[i] = ldf(p.Wm, i, bf);
        wv_s[i] = ldf(p.Wv, i, bf);
    }
    __syncthreads();
    const int c = threadIdx.x & 31, seg = threadIdx.x >> 5;
    const int d = blockIdx.x * 8 + seg;              // 2500*8 = 20000 exact
    const int deg = min(p.cnt[d], CAP);
    const int base = d * CAP;
    const float advd = p.a3d[d];
    float s = 0;
    for (int i = c; i < deg; i += 32) {
        int src = p.csr[base + i];
        float v = p.a3s[src] + advd;
        v = v > 0.f ? v : NSL * v;
        float ev = __expf(v);
        s += ev;
        lal[seg][i] = ev;
        lof[seg][i] = src * 32;
    }
    float acc = 0.0f;
    int e = 0;
    for (; e + 4 <= deg; e += 4) {
        float ev0 = lal[seg][e], ev1 = lal[seg][e + 1];
        float ev2 = lal[seg][e + 2], ev3 = lal[seg][e + 3];
        int o0 = lof[seg][e], o1 = lof[seg][e + 1];
        int o2 = lof[seg][e + 2], o3 = lof[seg][e + 3];
        float h0 = bits2f(p.h3[o0 + c]), h1 = bits2f(p.h3[o1 + c]);
        float h2 = bits2f(p.h3[o2 + c]), h3v = bits2f(p.h3[o3 + c]);
        acc = fmaf(ev0, h0, acc);
        acc = fmaf(ev1, h1, acc);
        acc = fmaf(ev2, h2, acc);
        acc = fmaf(ev3, h3v, acc);
    }
    for (; e < deg; ++e) acc = fmaf(lal[seg][e], bits2f(p.h3[lof[seg][e] + c]), acc);
#pragma unroll
    for (int off = 1; off < 32; off <<= 1) s += __shfl_xor(s, off, 32);
    const float inv = 1.0f / (s + 1e-16f);
    const float z = inv * acc + ldf(p.b3, c, bf);
    stf(p.out, (size_t)2 * Nn * 32 + (size_t)d * 32 + c, z, bf);   // z
    float sm = ldf(p.bm, c, bf), sv = ldf(p.bv, c, bf);
#pragma unroll 8
    for (int k = 0; k < 32; ++k) {
        float zk = __shfl(z, k, 32);
        sm = fmaf(zk, wm_s[k * 32 + c], sm);
        sv = fmaf(zk, wv_s[k * 32 + c], sv);
    }
    float var = __expf(sv);
    var = fminf(fmaxf(var, 1e-8f), 100.0f);
    stf(p.out, (size_t)d * 32 + c, sm, bf);                        // z_mean
    stf(p.out, (size_t)Nn * 32 + (size_t)d * 32 + c, var, bf);     // z_var
}

// ---------- launch: memset + 6 dispatches ----------
extern "C" void kernel_launch(void* const* d_in, const int* in_sizes, int n_in,
                              void* d_out, int out_size, void* d_ws, size_t ws_size,
                              hipStream_t stream) {
    float* ws = (float*)d_ws;
    MP p;
    p.x   = d_in[0];  p.ei  = (const int*)d_in[1];
    p.W1  = d_in[2];  p.as1 = d_in[3];  p.ad1 = d_in[4];  p.b1 = d_in[5];
    p.W2  = d_in[6];  p.as2 = d_in[7];  p.ad2 = d_in[8];  p.b2 = d_in[9];
    p.W3  = d_in[10]; p.as3 = d_in[11]; p.ad3 = d_in[12]; p.b3 = d_in[13];
    p.Wm  = d_in[14]; p.bm  = d_in[15]; p.Wv  = d_in[16]; p.bv = d_in[17];
    p.aggn = (ushortT*)ws;                    // 20000*512 bf16
    p.xb   = (ushortT*)(ws + 5120000);        // 20000*128 bf16
    p.x1b  = (ushortT*)(ws + 6400000);        // 20000*64 bf16
    p.h3   = (ushortT*)(ws + 7040000);        // 20000*32 bf16
    p.a1s  = ws + 7360000;                    // 80,000
    p.a1d  = ws + 7440000;                    // 80,000
    p.a2s  = ws + 7520000;                    // 80,000
    p.a2d  = ws + 7600000;                    // 80,000
    p.a3s  = ws + 7680000;                    // 20,000
    p.a3d  = ws + 7700000;                    // 20,000
    p.WT1c = (ushortT*)(ws + 7720000);        // 64*512 bf16
    p.WT2c = (ushortT*)(ws + 7736384);        // 64*256 bf16
    p.wp2  = ws + 7745600;                    // 512
    p.cnt  = (int*)(ws + 7746112);            // 20,000
    p.csr  = (int*)(ws + 7766112);            // 2,560,000
    p.eflag = (int*)(ws + 10326112);
    p.fflag = (int*)(ws + 10326113);
    p.out  = d_out;

    hipMemsetAsync(p.cnt, 0, 20000 * sizeof(int), stream);
    prep_k<<<2500, 256, 0, stream>>>(p);
    aggx128_k<<<5000, 256, 0, stream>>>(p);
    cat1_k<<<313, 256, 0, stream>>>(p);
    aggx64_k<<<5000, 256, 0, stream>>>(p);
    cat2s_k<<<313, 256, 0, stream>>>(p);
    aggr1f_k<<<2500, 256, 0, stream>>>(p);
}

// Round 7
// 288.864 us; speedup vs baseline: 3.6510x; 2.0652x over previous
//
#include <hip/hip_runtime.h>
#include <hip/hip_bf16.h>

typedef unsigned short ushortT;
typedef short short8 __attribute__((ext_vector_type(8)));
typedef unsigned short ushort8v __attribute__((ext_vector_type(8)));
typedef float float4v __attribute__((ext_vector_type(4)));

// Problem constants (from reference)
constexpr int Nn   = 20000;
constexpr int Ee   = 320000;
constexpr int EP   = Ee + Nn;     // edges + self loops
constexpr float NSL = 0.2f;       // leaky_relu negative slope
constexpr int CAP  = 128;         // per-dst bucket capacity

// ---------- helpers ----------
__device__ __forceinline__ float b2f(__hip_bfloat16 v) { return __bfloat162float(v); }
__device__ __forceinline__ float bits2f(unsigned short u) {
    __hip_bfloat16 b; *(unsigned short*)&b = u; return __bfloat162float(b);
}
__device__ __forceinline__ unsigned short f2bits(float v) {
    __hip_bfloat16 b = __float2bfloat16(v); return *(unsigned short*)&b;
}
__device__ __forceinline__ float ldf(const void* p, size_t i, int bf) {
    return bf ? __bfloat162float(((const __hip_bfloat16*)p)[i])
              : ((const float*)p)[i];
}
__device__ __forceinline__ void stf(void* p, size_t i, float v, int bf) {
    if (bf) ((__hip_bfloat16*)p)[i] = __float2bfloat16(v);
    else    ((float*)p)[i] = v;
}

// vectorized dot of 64 consecutive elems (bf16 or f32), ascending order (bitwise
// identical to the scalar ascending loop it replaces)
__device__ __forceinline__ float dot64_vec(const void* W, size_t woff,
                                           const void* av, size_t aoff, int bf) {
    float acc = 0.f;
    if (bf) {
        const ushortT* Wr = (const ushortT*)W + woff;
        const ushortT* Ar = (const ushortT*)av + aoff;
#pragma unroll
        for (int c8 = 0; c8 < 64; c8 += 8) {
            ushort8v wv = *(const ushort8v*)(Wr + c8);
            ushort8v avv = *(const ushort8v*)(Ar + c8);
#pragma unroll
            for (int j = 0; j < 8; ++j)
                acc = fmaf(bits2f(wv[j]), bits2f(avv[j]), acc);
        }
    } else {
        const float* Wr = (const float*)W + woff;
        const float* Ar = (const float*)av + aoff;
#pragma unroll
        for (int c4 = 0; c4 < 64; c4 += 4) {
            float4 wv = *(const float4*)(Wr + c4);
            float4 avv = *(const float4*)(Ar + c4);
            acc = fmaf(wv.x, avv.x, acc);
            acc = fmaf(wv.y, avv.y, acc);
            acc = fmaf(wv.z, avv.z, acc);
            acc = fmaf(wv.w, avv.w, acc);
        }
    }
    return acc;
}

// ---------- parameter block ----------
struct MP {
    const void* x; const int* ei;
    const void* W1; const void* as1; const void* ad1; const void* b1;
    const void* W2; const void* as2; const void* ad2; const void* b2;
    const void* W3; const void* as3; const void* ad3; const void* b3;
    const void* Wm; const void* bm; const void* Wv; const void* bv;
    ushortT* aggn; ushortT* xb; ushortT* x1b; ushortT* h3;
    float* a1s; float* a1d; float* a2s; float* a2d; float* a3s; float* a3d;
    ushortT* WT1c; ushortT* WT2c; float* wp2;
    int* cnt; int* csr; int* eflag; int* fflag;
    void* out;
};

// ---------- K1: prep = flags(local) + scatter + W transposes + wp2 + alpha1 ----------
// grid MUST be exactly 2500 (alpha covers 2500*8 = 20000 nodes).
// wp1 recomputed per-block into LDS with VECTORIZED loads (R6's scalar version was
// 328M scalar 2-byte loads device-wide = 438us; vector form is 20M 16-byte loads).
__global__ __launch_bounds__(256) void prep_k(MP p) {
    __shared__ float wp1_s[1024];
    __shared__ int c_s, bad_s;
    if (threadIdx.x == 0) { c_s = 0; bad_s = 0; }
    __syncthreads();
    {
        const unsigned* xbits = (const unsigned*)p.x;
        int c = 0;
        for (int i = threadIdx.x; i < 512; i += 256) {
            unsigned e = (xbits[i] >> 7) & 0xFFu;
            if (e >= 110u && e <= 135u) ++c;
        }
        atomicAdd(&c_s, c);
        for (int i = threadIdx.x; i < 1024; i += 256)
            if (p.ei[2 * i + 1] != 0) bad_s = 1;     // benign multi-write of 1
    }
    __syncthreads();
    const int bf = (c_s > 384) ? 1 : 0;   // 1 => floats delivered as bf16
    const int sh = bad_s ? 0 : 1;         // 1 => int64 edge_index layout
    if (blockIdx.x == 0 && threadIdx.x == 0) { *p.eflag = sh; *p.fflag = bf; }

    // scatter slice (cnt pre-zeroed by hipMemsetAsync)
    for (int e = blockIdx.x * 256 + threadIdx.x; e < EP; e += gridDim.x * 256) {
        int si, di;
        if (e < Ee) {
            si = p.ei[(size_t)e << sh];
            di = p.ei[(size_t)(Ee + e) << sh];
        } else {
            si = di = e - Ee;   // self loop
        }
        int pos = atomicAdd(p.cnt + di, 1);
        if (pos < CAP) p.csr[di * CAP + pos] = si;
    }

    // weight transposes (blocks 0..191) / wp2 projection (block 192, vectorized)
    if (blockIdx.x < 192) {
        int idx = blockIdx.x * 256 + threadIdx.x;    // < 49152
        if (idx < 32768) {
            int jp = idx >> 9, r = idx & 511, hh = r >> 7, k = r & 127;
            p.WT1c[idx] = f2bits(ldf(p.W1, (size_t)k * 256 + hh * 64 + jp, bf));
        } else {
            int i2 = idx - 32768;                    // < 16384
            int jp = i2 >> 8, r = i2 & 255, hh = r >> 6, k = r & 63;
            p.WT2c[i2] = f2bits(ldf(p.W2, (size_t)k * 256 + hh * 64 + jp, bf));
        }
    } else if (blockIdx.x == 192) {
        for (int i2 = threadIdx.x; i2 < 512; i2 += 256) {
            int sd = i2 >> 8, r = i2 & 255, hh = r >> 6, k = r & 63;
            const void* av = sd ? p.ad2 : p.as2;
            p.wp2[i2] = dot64_vec(p.W2, (size_t)k * 256 + hh * 64, av, hh * 64, bf);
        }
    }

    // wp1 into LDS (every block; vectorized; same ascending-c order -> bitwise identical)
    for (int t = threadIdx.x; t < 1024; t += 256) {
        int sd = t >> 9, hh = (t >> 7) & 3, k = t & 127;
        const void* av = sd ? p.ad1 : p.as1;
        wp1_s[t] = dot64_vec(p.W1, (size_t)k * 256 + hh * 64, av, hh * 64, bf);
    }
    __syncthreads();

    // layer-1 alphas + x -> bf16 cast (8 nodes per block)
    const int cl = threadIdx.x & 31, g = threadIdx.x >> 5;
    const int n = blockIdx.x * 8 + g;                // grid 2500 exact -> n < 20000
    const int c4 = cl * 4;
    float xv[4];
    if (bf) {
        ushort4 u = *(const ushort4*)((const ushortT*)p.x + (size_t)n * 128 + c4);
        xv[0] = bits2f(u.x); xv[1] = bits2f(u.y); xv[2] = bits2f(u.z); xv[3] = bits2f(u.w);
        *(ushort4*)(p.xb + (size_t)n * 128 + c4) = u;
    } else {
        float4 f = *(const float4*)((const float*)p.x + (size_t)n * 128 + c4);
        xv[0] = f.x; xv[1] = f.y; xv[2] = f.z; xv[3] = f.w;
        ushort4 u;
        u.x = f2bits(f.x); u.y = f2bits(f.y); u.z = f2bits(f.z); u.w = f2bits(f.w);
        *(ushort4*)(p.xb + (size_t)n * 128 + c4) = u;
    }
    float pr[8];
#pragma unroll
    for (int j = 0; j < 8; ++j) {
        const float* wv = wp1_s + j * 128 + c4;
        float t = 0.f;
        t = fmaf(xv[0], wv[0], t);
        t = fmaf(xv[1], wv[1], t);
        t = fmaf(xv[2], wv[2], t);
        t = fmaf(xv[3], wv[3], t);
        pr[j] = t;
    }
#pragma unroll
    for (int off = 1; off < 32; off <<= 1) {
#pragma unroll
        for (int j = 0; j < 8; ++j) pr[j] += __shfl_xor(pr[j], off, 32);
    }
    if (cl == 0) {
        *(float4*)(p.a1s + (size_t)n * 4) = make_float4(pr[0], pr[1], pr[2], pr[3]);
        *(float4*)(p.a1d + (size_t)n * 4) = make_float4(pr[4], pr[5], pr[6], pr[7]);
    }
}

// ---------- per-edge eval helper ----------
__device__ __forceinline__ void edge_evals(const float* as_, int src, const float4& adv,
                                           float& s0, float& s1, float& s2, float& s3,
                                           float* slot) {
    float4 av = *(const float4*)(as_ + src * 4);
    float v0 = av.x + adv.x; v0 = v0 > 0.f ? v0 : NSL * v0; float e0 = __expf(v0);
    float v1 = av.y + adv.y; v1 = v1 > 0.f ? v1 : NSL * v1; float e1 = __expf(v1);
    float v2 = av.z + adv.z; v2 = v2 > 0.f ? v2 : NSL * v2; float e2 = __expf(v2);
    float v3 = av.w + adv.w; v3 = v3 > 0.f ? v3 : NSL * v3; float e3 = __expf(v3);
    s0 += e0; s1 += e1; s2 += e2; s3 += e3;
    *(float4*)slot = make_float4(e0, e1, e2, e3);
}

// ---------- K2: aggregate-first layer 1 (CIN=128); src offsets staged in LDS ----------
__global__ __launch_bounds__(256) void aggx128_k(MP p) {
    __shared__ float lal[4][CAP][4];
    __shared__ int   lsrc[4][CAP];
    const int lane = threadIdx.x & 63, seg = threadIdx.x >> 6;
    const int d = blockIdx.x * 4 + seg;              // 5000*4 = 20000 exact
    const int deg = min(p.cnt[d], CAP);
    const int base = d * CAP;
    const float4 adv = *(const float4*)(p.a1d + d * 4);
    const int src0 = (lane < deg) ? p.csr[base + lane] : 0;
    const int src1 = (64 + lane < deg) ? p.csr[base + 64 + lane] : 0;
    float s0 = 0, s1 = 0, s2 = 0, s3 = 0;
    if (lane < deg) {
        edge_evals(p.a1s, src0, adv, s0, s1, s2, s3, &lal[seg][lane][0]);
        lsrc[seg][lane] = src0 * 128;
    }
    if (64 + lane < deg) {
        edge_evals(p.a1s, src1, adv, s0, s1, s2, s3, &lal[seg][64 + lane][0]);
        lsrc[seg][64 + lane] = src1 * 128;
    }
    const int q = lane >> 4, c8 = (lane & 15) * 8;
    const float* lal_s = &lal[seg][0][0];
    const int* lsrc_s = &lsrc[seg][0];
    float a[8] = {0, 0, 0, 0, 0, 0, 0, 0};

    auto do_edge = [&](int idx) {
        float ev = lal_s[idx * 4 + q];               // broadcast within q-group
        int sof = lsrc_s[idx];                       // broadcast
        ushort8v xv = *(const ushort8v*)(p.xb + (size_t)sof + c8);
#pragma unroll
        for (int j = 0; j < 8; ++j) a[j] = fmaf(ev, bits2f(xv[j]), a[j]);
    };

    int e = 0;
    for (; e + 4 <= deg; e += 4) {
        do_edge(e); do_edge(e + 1); do_edge(e + 2); do_edge(e + 3);
    }
    for (; e < deg; ++e) do_edge(e);

#pragma unroll
    for (int off = 1; off < 64; off <<= 1) {
        s0 += __shfl_xor(s0, off, 64);
        s1 += __shfl_xor(s1, off, 64);
        s2 += __shfl_xor(s2, off, 64);
        s3 += __shfl_xor(s3, off, 64);
    }
    const float sq = (q == 0) ? s0 : (q == 1) ? s1 : (q == 2) ? s2 : s3;
    const float iq = 0.25f / (sq + 1e-16f);
    ushort8v pk;
#pragma unroll
    for (int j = 0; j < 8; ++j) pk[j] = f2bits(a[j] * iq);
    *(ushort8v*)(p.aggn + (size_t)d * 512 + q * 128 + c8) = pk;
}

// ---------- K4: aggregate-first layer 2 (CIN=64); src offsets staged in LDS ----------
__global__ __launch_bounds__(256) void aggx64_k(MP p) {
    __shared__ float lal[4][CAP][4];
    __shared__ int   lsrc[4][CAP];
    const int lane = threadIdx.x & 63, seg = threadIdx.x >> 6;
    const int d = blockIdx.x * 4 + seg;
    const int deg = min(p.cnt[d], CAP);
    const int base = d * CAP;
    const float4 adv = *(const float4*)(p.a2d + d * 4);
    const int src0 = (lane < deg) ? p.csr[base + lane] : 0;
    const int src1 = (64 + lane < deg) ? p.csr[base + 64 + lane] : 0;
    float s0 = 0, s1 = 0, s2 = 0, s3 = 0;
    if (lane < deg) {
        edge_evals(p.a2s, src0, adv, s0, s1, s2, s3, &lal[seg][lane][0]);
        lsrc[seg][lane] = src0 * 64;
    }
    if (64 + lane < deg) {
        edge_evals(p.a2s, src1, adv, s0, s1, s2, s3, &lal[seg][64 + lane][0]);
        lsrc[seg][64 + lane] = src1 * 64;
    }
    const int hl = lane >> 5, cl = lane & 31;
    const int q = cl >> 3, c8 = (cl & 7) * 8;
    const float* lal_s = &lal[seg][0][0];
    const int* lsrc_s = &lsrc[seg][0];
    float a[8] = {0, 0, 0, 0, 0, 0, 0, 0};

    auto do_edge = [&](int idx, bool valid) {
        float ev = valid ? lal_s[idx * 4 + q] : 0.0f;
        int off = valid ? lsrc_s[idx] : 0;
        ushort8v xv = *(const ushort8v*)(p.x1b + (size_t)off + c8);
#pragma unroll
        for (int j = 0; j < 8; ++j) a[j] = fmaf(ev, bits2f(xv[j]), a[j]);
    };

    int e = 0;
    for (; e + 8 <= deg; e += 8) {
        do_edge(e + hl, true);
        do_edge(e + 2 + hl, true);
        do_edge(e + 4 + hl, true);
        do_edge(e + 6 + hl, true);
    }
    for (; e < deg; e += 2) do_edge(e + hl, (e + hl) < deg);

#pragma unroll
    for (int off = 1; off < 64; off <<= 1) {
        s0 += __shfl_xor(s0, off, 64);
        s1 += __shfl_xor(s1, off, 64);
        s2 += __shfl_xor(s2, off, 64);
        s3 += __shfl_xor(s3, off, 64);
    }
#pragma unroll
    for (int j = 0; j < 8; ++j) a[j] += __shfl_xor(a[j], 32, 64);
    const float sq = (q == 0) ? s0 : (q == 1) ? s1 : (q == 2) ? s2 : s3;
    const float iq = 0.25f / (sq + 1e-16f);
    if (hl == 0) {
        ushort8v pk;
#pragma unroll
        for (int j = 0; j < 8; ++j) pk[j] = f2bits(a[j] * iq);
        *(ushort8v*)(p.aggn + (size_t)d * 256 + q * 64 + c8) = pk;
    }
}

// ---------- K3: layer-1 transform (MFMA) + fused layer-2 alphas ----------
__global__ __launch_bounds__(256) void cat1_k(MP p) {
    constexpr int K = 512, KC = 128, SW = KC + 8, NCH = K / KC;
    __shared__ ushortT wt_s[64 * SW];
    __shared__ ushortT xs[64 * SW];
    __shared__ float wp_s[512];
    const int bf = *p.fflag;
    const int lane = threadIdx.x & 63, w = threadIdx.x >> 6;
    const int ln = lane & 15, quad = lane >> 4;
    const int base = blockIdx.x * 64;                // grid 313
    float4v acc[4];
#pragma unroll
    for (int T = 0; T < 4; ++T) acc[T] = (float4v){0.f, 0.f, 0.f, 0.f};
    for (int i = threadIdx.x; i < 512; i += 256) wp_s[i] = p.wp2[i];
#pragma unroll
    for (int ch = 0; ch < NCH; ++ch) {
        for (int i = threadIdx.x; i < 64 * 16; i += 256) {
            int r = i >> 4, kc = (i & 15) * 8;
            *(short8*)(wt_s + r * SW + kc) =
                *(const short8*)(p.WT1c + (size_t)r * K + ch * KC + kc);
            int node = base + r;
            short8 v = {0, 0, 0, 0, 0, 0, 0, 0};
            if (node < Nn) v = *(const short8*)(p.aggn + (size_t)node * K + ch * KC + kc);
            *(short8*)(xs + r * SW + kc) = v;
        }
        __syncthreads();
#pragma unroll
        for (int ks = 0; ks < 4; ++ks) {
            const int kb = ks * 32 + quad * 8;
            const short8 bfr = *(const short8*)(xs + (w * 16 + ln) * SW + kb);
#pragma unroll
            for (int T = 0; T < 4; ++T) {
                const short8 afr = *(const short8*)(wt_s + (T * 16 + ln) * SW + kb);
                acc[T] = __builtin_amdgcn_mfma_f32_16x16x32_bf16(afr, bfr, acc[T], 0, 0, 0);
            }
        }
        __syncthreads();
    }
    const int node = base + w * 16 + ln;
    const bool live = node < Nn;
    ushortT* on = p.x1b + (size_t)node * 64;
    float pr[8];
#pragma unroll
    for (int j = 0; j < 8; ++j) pr[j] = 0.f;
#pragma unroll
    for (int T = 0; T < 4; ++T) {
        const int jl = T * 16 + quad * 4;
        ushort4 pk;
        float t0 = fmaxf(acc[T][0] + ldf(p.b1, jl + 0, bf), 0.f);
        float t1 = fmaxf(acc[T][1] + ldf(p.b1, jl + 1, bf), 0.f);
        float t2 = fmaxf(acc[T][2] + ldf(p.b1, jl + 2, bf), 0.f);
        float t3 = fmaxf(acc[T][3] + ldf(p.b1, jl + 3, bf), 0.f);
        pk.x = f2bits(t0); pk.y = f2bits(t1); pk.z = f2bits(t2); pk.w = f2bits(t3);
        if (live) *(ushort4*)(on + jl) = pk;
#pragma unroll
        for (int j = 0; j < 8; ++j) {
            pr[j] = fmaf(t0, wp_s[j * 64 + jl + 0], pr[j]);
            pr[j] = fmaf(t1, wp_s[j * 64 + jl + 1], pr[j]);
            pr[j] = fmaf(t2, wp_s[j * 64 + jl + 2], pr[j]);
            pr[j] = fmaf(t3, wp_s[j * 64 + jl + 3], pr[j]);
        }
    }
#pragma unroll
    for (int j = 0; j < 8; ++j) {
        pr[j] += __shfl_xor(pr[j], 16, 64);
        pr[j] += __shfl_xor(pr[j], 32, 64);
    }
    if (quad == 0 && live) {
        *(float4*)(p.a2s + (size_t)node * 4) = make_float4(pr[0], pr[1], pr[2], pr[3]);
        *(float4*)(p.a2d + (size_t)node * 4) = make_float4(pr[4], pr[5], pr[6], pr[7]);
    }
}

// ---------- K5: layer-2 transform + layer-3 GEMM fused per tile ----------
__global__ __launch_bounds__(256) void cat2s_k(MP p) {
    constexpr int K = 256, KC = 128, SW = KC + 8, NCH = K / KC, PAD = 36;
    __shared__ __align__(16) char pool[36864];
    ushortT* wt_s = (ushortT*)pool;                       // 17408 B (MFMA part)
    ushortT* xs   = (ushortT*)(pool + 17408);             // 17408 B (MFMA part)
    ushortT* x2t  = (ushortT*)pool;                       // 8192 B (reuse after MFMA)
    float*   xsh  = (float*)(pool + 8192);                // 9216 B
    const int bf = *p.fflag;
    const int lane = threadIdx.x & 63, w = threadIdx.x >> 6;
    const int ln = lane & 15, quad = lane >> 4;
    const int jc = threadIdx.x & 31, g = threadIdx.x >> 5;
    const int base = blockIdx.x * 64;                // grid 313
    float4v acc[4];
#pragma unroll
    for (int T = 0; T < 4; ++T) acc[T] = (float4v){0.f, 0.f, 0.f, 0.f};
#pragma unroll
    for (int ch = 0; ch < NCH; ++ch) {
        for (int i = threadIdx.x; i < 64 * 16; i += 256) {
            int r = i >> 4, kc = (i & 15) * 8;
            *(short8*)(wt_s + r * SW + kc) =
                *(const short8*)(p.WT2c + (size_t)r * K + ch * KC + kc);
            int node = base + r;
            short8 v = {0, 0, 0, 0, 0, 0, 0, 0};
            if (node < Nn) v = *(const short8*)(p.aggn + (size_t)node * K + ch * KC + kc);
            *(short8*)(xs + r * SW + kc) = v;
        }
        __syncthreads();
#pragma unroll
        for (int ks = 0; ks < 4; ++ks) {
            const int kb = ks * 32 + quad * 8;
            const short8 bfr = *(const short8*)(xs + (w * 16 + ln) * SW + kb);
#pragma unroll
            for (int T = 0; T < 4; ++T) {
                const short8 afr = *(const short8*)(wt_s + (T * 16 + ln) * SW + kb);
                acc[T] = __builtin_amdgcn_mfma_f32_16x16x32_bf16(afr, bfr, acc[T], 0, 0, 0);
            }
        }
        __syncthreads();
    }
    // epilogue: x2 = relu(acc + b2) -> LDS tile
#pragma unroll
    for (int T = 0; T < 4; ++T) {
        const int jl = T * 16 + quad * 4;
        ushort4 pk;
        pk.x = f2bits(fmaxf(acc[T][0] + ldf(p.b2, jl + 0, bf), 0.f));
        pk.y = f2bits(fmaxf(acc[T][1] + ldf(p.b2, jl + 1, bf), 0.f));
        pk.z = f2bits(fmaxf(acc[T][2] + ldf(p.b2, jl + 2, bf), 0.f));
        pk.w = f2bits(fmaxf(acc[T][3] + ldf(p.b2, jl + 3, bf), 0.f));
        *(ushort4*)(x2t + (w * 16 + ln) * 64 + jl) = pk;
    }
    __syncthreads();
    // layer-3 small GEMM on the tile (2 sub-blocks of 32 nodes)
    float avsr = ldf(p.as3, jc, bf), avdr = ldf(p.ad3, jc, bf);
#pragma unroll
    for (int sub = 0; sub < 2; ++sub) {
        for (int i = threadIdx.x; i < 32 * 64; i += 256) {
            int rr = i >> 6, kk = i & 63;
            xsh[kk * PAD + rr] = bits2f(x2t[(sub * 32 + rr) * 64 + kk]);
        }
        __syncthreads();
        float accs[4] = {};
        if (bf) {
            const __hip_bfloat16* Wb = (const __hip_bfloat16*)p.W3;
#pragma unroll 4
            for (int k = 0; k < 64; ++k) {
                float4 xv = *(const float4*)(xsh + k * PAD + g * 4);
                float wv = b2f(Wb[k * 32 + jc]);
                accs[0] = fmaf(xv.x, wv, accs[0]);
                accs[1] = fmaf(xv.y, wv, accs[1]);
                accs[2] = fmaf(xv.z, wv, accs[2]);
                accs[3] = fmaf(xv.w, wv, accs[3]);
            }
        } else {
            const float* Wf = (const float*)p.W3;
#pragma unroll 4
            for (int k = 0; k < 64; ++k) {
                float4 xv = *(const float4*)(xsh + k * PAD + g * 4);
                float wv = Wf[k * 32 + jc];
                accs[0] = fmaf(xv.x, wv, accs[0]);
                accs[1] = fmaf(xv.y, wv, accs[1]);
                accs[2] = fmaf(xv.z, wv, accs[2]);
                accs[3] = fmaf(xv.w, wv, accs[3]);
            }
        }
#pragma unroll
        for (int m = 0; m < 4; ++m) {
            int n = base + sub * 32 + g * 4 + m;
            if (n < Nn) {
                p.h3[(size_t)n * 32 + jc] = f2bits(accs[m]);
                float t1 = accs[m] * avsr;
                float t2 = accs[m] * avdr;
#pragma unroll
                for (int off = 16; off > 0; off >>= 1) {
                    t1 += __shfl_down(t1, off, 32);
                    t2 += __shfl_down(t2, off, 32);
                }
                if (jc == 0) { p.a3s[n] = t1; p.a3d[n] = t2; }
            }
        }
        __syncthreads();
    }
}

// ---------- K6: layer-3 aggregation fused with output heads ----------
__global__ __launch_bounds__(256) void aggr1f_k(MP p) {
    __shared__ float wm_s[1024], wv_s[1024];
    __shared__ float lal[8][CAP];
    __shared__ int   lof[8][CAP];
    const int bf = *p.fflag;
    for (int i = threadIdx.x; i < 1024; i += 256) {
        wm_s[i] = ldf(p.Wm, i, bf);
        wv_s[i] = ldf(p.Wv, i, bf);
    }
    __syncthreads();
    const int c = threadIdx.x & 31, seg = threadIdx.x >> 5;
    const int d = blockIdx.x * 8 + seg;              // 2500*8 = 20000 exact
    const int deg = min(p.cnt[d], CAP);
    const int base = d * CAP;
    const float advd = p.a3d[d];
    float s = 0;
    for (int i = c; i < deg; i += 32) {
        int src = p.csr[base + i];
        float v = p.a3s[src] + advd;
        v = v > 0.f ? v : NSL * v;
        float ev = __expf(v);
        s += ev;
        lal[seg][i] = ev;
        lof[seg][i] = src * 32;
    }
    float acc = 0.0f;
    int e = 0;
    for (; e + 4 <= deg; e += 4) {
        float ev0 = lal[seg][e], ev1 = lal[seg][e + 1];
        float ev2 = lal[seg][e + 2], ev3 = lal[seg][e + 3];
        int o0 = lof[seg][e], o1 = lof[seg][e + 1];
        int o2 = lof[seg][e + 2], o3 = lof[seg][e + 3];
        float h0 = bits2f(p.h3[o0 + c]), h1 = bits2f(p.h3[o1 + c]);
        float h2 = bits2f(p.h3[o2 + c]), h3v = bits2f(p.h3[o3 + c]);
        acc = fmaf(ev0, h0, acc);
        acc = fmaf(ev1, h1, acc);
        acc = fmaf(ev2, h2, acc);
        acc = fmaf(ev3, h3v, acc);
    }
    for (; e < deg; ++e) acc = fmaf(lal[seg][e], bits2f(p.h3[lof[seg][e] + c]), acc);
#pragma unroll
    for (int off = 1; off < 32; off <<= 1) s += __shfl_xor(s, off, 32);
    const float inv = 1.0f / (s + 1e-16f);
    const float z = inv * acc + ldf(p.b3, c, bf);
    stf(p.out, (size_t)2 * Nn * 32 + (size_t)d * 32 + c, z, bf);   // z
    float sm = ldf(p.bm, c, bf), sv = ldf(p.bv, c, bf);
#pragma unroll 8
    for (int k = 0; k < 32; ++k) {
        float zk = __shfl(z, k, 32);
        sm = fmaf(zk, wm_s[k * 32 + c], sm);
        sv = fmaf(zk, wv_s[k * 32 + c], sv);
    }
    float var = __expf(sv);
    var = fminf(fmaxf(var, 1e-8f), 100.0f);
    stf(p.out, (size_t)d * 32 + c, sm, bf);                        // z_mean
    stf(p.out, (size_t)Nn * 32 + (size_t)d * 32 + c, var, bf);     // z_var
}

// ---------- launch: memset + 6 dispatches ----------
extern "C" void kernel_launch(void* const* d_in, const int* in_sizes, int n_in,
                              void* d_out, int out_size, void* d_ws, size_t ws_size,
                              hipStream_t stream) {
    float* ws = (float*)d_ws;
    MP p;
    p.x   = d_in[0];  p.ei  = (const int*)d_in[1];
    p.W1  = d_in[2];  p.as1 = d_in[3];  p.ad1 = d_in[4];  p.b1 = d_in[5];
    p.W2  = d_in[6];  p.as2 = d_in[7];  p.ad2 = d_in[8];  p.b2 = d_in[9];
    p.W3  = d_in[10]; p.as3 = d_in[11]; p.ad3 = d_in[12]; p.b3 = d_in[13];
    p.Wm  = d_in[14]; p.bm  = d_in[15]; p.Wv  = d_in[16]; p.bv = d_in[17];
    p.aggn = (ushortT*)ws;                    // 20000*512 bf16
    p.xb   = (ushortT*)(ws + 5120000);        // 20000*128 bf16
    p.x1b  = (ushortT*)(ws + 6400000);        // 20000*64 bf16
    p.h3   = (ushortT*)(ws + 7040000);        // 20000*32 bf16
    p.a1s  = ws + 7360000;                    // 80,000
    p.a1d  = ws + 7440000;                    // 80,000
    p.a2s  = ws + 7520000;                    // 80,000
    p.a2d  = ws + 7600000;                    // 80,000
    p.a3s  = ws + 7680000;                    // 20,000
    p.a3d  = ws + 7700000;                    // 20,000
    p.WT1c = (ushortT*)(ws + 7720000);        // 64*512 bf16
    p.WT2c = (ushortT*)(ws + 7736384);        // 64*256 bf16
    p.wp2  = ws + 7745600;                    // 512
    p.cnt  = (int*)(ws + 7746112);            // 20,000
    p.csr  = (int*)(ws + 7766112);            // 2,560,000
    p.eflag = (int*)(ws + 10326112);
    p.fflag = (int*)(ws + 10326113);
    p.out  = d_out;

    hipMemsetAsync(p.cnt, 0, 20000 * sizeof(int), stream);
    prep_k<<<2500, 256, 0, stream>>>(p);
    aggx128_k<<<5000, 256, 0, stream>>>(p);
    cat1_k<<<313, 256, 0, stream>>>(p);
    aggx64_k<<<5000, 256, 0, stream>>>(p);
    cat2s_k<<<313, 256, 0, stream>>>(p);
    aggr1f_k<<<2500, 256, 0, stream>>>(p);
}

// Round 9
// 233.147 us; speedup vs baseline: 4.5234x; 1.2390x over previous
//
#include <hip/hip_runtime.h>
#include <hip/hip_bf16.h>

typedef unsigned short ushortT;
typedef short short8 __attribute__((ext_vector_type(8)));
typedef unsigned short ushort8v __attribute__((ext_vector_type(8)));
typedef float float4v __attribute__((ext_vector_type(4)));

// Problem constants (from reference)
constexpr int Nn   = 20000;
constexpr int Ee   = 320000;
constexpr int EP   = Ee + Nn;     // edges + self loops
constexpr float NSL = 0.2f;       // leaky_relu negative slope
constexpr int CAP  = 128;         // per-dst bucket capacity

// ---------- helpers ----------
__device__ __forceinline__ float b2f(__hip_bfloat16 v) { return __bfloat162float(v); }
__device__ __forceinline__ float bits2f(unsigned short u) {
    __hip_bfloat16 b; *(unsigned short*)&b = u; return __bfloat162float(b);
}
__device__ __forceinline__ unsigned short f2bits(float v) {
    __hip_bfloat16 b = __float2bfloat16(v); return *(unsigned short*)&b;
}
__device__ __forceinline__ float ldf(const void* p, size_t i, int bf) {
    return bf ? __bfloat162float(((const __hip_bfloat16*)p)[i])
              : ((const float*)p)[i];
}
__device__ __forceinline__ void stf(void* p, size_t i, float v, int bf) {
    if (bf) ((__hip_bfloat16*)p)[i] = __float2bfloat16(v);
    else    ((float*)p)[i] = v;
}

// vectorized dot of 64 consecutive elems (bf16 or f32), ascending order (bitwise
// identical to the scalar ascending loop it replaces)
__device__ __forceinline__ float dot64_vec(const void* W, size_t woff,
                                           const void* av, size_t aoff, int bf) {
    float acc = 0.f;
    if (bf) {
        const ushortT* Wr = (const ushortT*)W + woff;
        const ushortT* Ar = (const ushortT*)av + aoff;
#pragma unroll
        for (int c8 = 0; c8 < 64; c8 += 8) {
            ushort8v wv = *(const ushort8v*)(Wr + c8);
            ushort8v avv = *(const ushort8v*)(Ar + c8);
#pragma unroll
            for (int j = 0; j < 8; ++j)
                acc = fmaf(bits2f(wv[j]), bits2f(avv[j]), acc);
        }
    } else {
        const float* Wr = (const float*)W + woff;
        const float* Ar = (const float*)av + aoff;
#pragma unroll
        for (int c4 = 0; c4 < 64; c4 += 4) {
            float4 wv = *(const float4*)(Wr + c4);
            float4 avv = *(const float4*)(Ar + c4);
            acc = fmaf(wv.x, avv.x, acc);
            acc = fmaf(wv.y, avv.y, acc);
            acc = fmaf(wv.z, avv.z, acc);
            acc = fmaf(wv.w, avv.w, acc);
        }
    }
    return acc;
}

// ---------- parameter block ----------
struct MP {
    const void* x; const int* ei;
    const void* W1; const void* as1; const void* ad1; const void* b1;
    const void* W2; const void* as2; const void* ad2; const void* b2;
    const void* W3; const void* as3; const void* ad3; const void* b3;
    const void* Wm; const void* bm; const void* Wv; const void* bv;
    ushortT* aggn; ushortT* xb; ushortT* x1b; ushortT* h3;
    float* a1s; float* a1d; float* a2s; float* a2d; float* a3s; float* a3d;
    ushortT* WT1c; ushortT* WT2c; float* wp2;
    int* cnt; int* csr; int* eflag; int* fflag;
    void* out;
};

// ---------- K1: prep = flags(local) + scatter + W transposes + wp2 + alpha1 ----------
// grid MUST be exactly 625 (alpha covers 625 * 32 = 20000 nodes, 4 iters x 8/block).
// wp1 recomputed per-block into LDS (vectorized). R7 ran this at grid 2500 ->
// 41M redundant vector loads; grid 625 amortizes the same per-block cost over
// 4x the alpha work: 10M loads (~164MB L2), ~4us issue.
__global__ __launch_bounds__(256) void prep_k(MP p) {
    __shared__ float wp1_s[1024];
    __shared__ int c_s, bad_s;
    if (threadIdx.x == 0) { c_s = 0; bad_s = 0; }
    __syncthreads();
    {
        const unsigned* xbits = (const unsigned*)p.x;
        int c = 0;
        for (int i = threadIdx.x; i < 512; i += 256) {
            unsigned e = (xbits[i] >> 7) & 0xFFu;
            if (e >= 110u && e <= 135u) ++c;
        }
        atomicAdd(&c_s, c);
        for (int i = threadIdx.x; i < 1024; i += 256)
            if (p.ei[2 * i + 1] != 0) bad_s = 1;     // benign multi-write of 1
    }
    __syncthreads();
    const int bf = (c_s > 384) ? 1 : 0;   // 1 => floats delivered as bf16
    const int sh = bad_s ? 0 : 1;         // 1 => int64 edge_index layout
    if (blockIdx.x == 0 && threadIdx.x == 0) { *p.eflag = sh; *p.fflag = bf; }

    // scatter slice (cnt pre-zeroed by hipMemsetAsync); ~2.1 edges/thread at grid 625
    for (int e = blockIdx.x * 256 + threadIdx.x; e < EP; e += gridDim.x * 256) {
        int si, di;
        if (e < Ee) {
            si = p.ei[(size_t)e << sh];
            di = p.ei[(size_t)(Ee + e) << sh];
        } else {
            si = di = e - Ee;   // self loop
        }
        int pos = atomicAdd(p.cnt + di, 1);
        if (pos < CAP) p.csr[di * CAP + pos] = si;
    }

    // weight transposes (blocks 0..191) / wp2 projection (block 192, vectorized)
    if (blockIdx.x < 192) {
        int idx = blockIdx.x * 256 + threadIdx.x;    // < 49152
        if (idx < 32768) {
            int jp = idx >> 9, r = idx & 511, hh = r >> 7, k = r & 127;
            p.WT1c[idx] = f2bits(ldf(p.W1, (size_t)k * 256 + hh * 64 + jp, bf));
        } else {
            int i2 = idx - 32768;                    // < 16384
            int jp = i2 >> 8, r = i2 & 255, hh = r >> 6, k = r & 63;
            p.WT2c[i2] = f2bits(ldf(p.W2, (size_t)k * 256 + hh * 64 + jp, bf));
        }
    } else if (blockIdx.x == 192) {
        for (int i2 = threadIdx.x; i2 < 512; i2 += 256) {
            int sd = i2 >> 8, r = i2 & 255, hh = r >> 6, k = r & 63;
            const void* av = sd ? p.ad2 : p.as2;
            p.wp2[i2] = dot64_vec(p.W2, (size_t)k * 256 + hh * 64, av, hh * 64, bf);
        }
    }

    // wp1 into LDS (every block; vectorized; same ascending-c order -> bitwise identical)
    for (int t = threadIdx.x; t < 1024; t += 256) {
        int sd = t >> 9, hh = (t >> 7) & 3, k = t & 127;
        const void* av = sd ? p.ad1 : p.as1;
        wp1_s[t] = dot64_vec(p.W1, (size_t)k * 256 + hh * 64, av, hh * 64, bf);
    }
    __syncthreads();

    // layer-1 alphas + x -> bf16 cast (32 nodes per block, 4 iterations x 8)
    const int cl = threadIdx.x & 31, g = threadIdx.x >> 5;
    const int c4 = cl * 4;
#pragma unroll 1
    for (int it = 0; it < 4; ++it) {
        const int n = blockIdx.x * 32 + it * 8 + g;  // grid 625 exact -> n < 20000
        float xv[4];
        if (bf) {
            ushort4 u = *(const ushort4*)((const ushortT*)p.x + (size_t)n * 128 + c4);
            xv[0] = bits2f(u.x); xv[1] = bits2f(u.y); xv[2] = bits2f(u.z); xv[3] = bits2f(u.w);
            *(ushort4*)(p.xb + (size_t)n * 128 + c4) = u;
        } else {
            float4 f = *(const float4*)((const float*)p.x + (size_t)n * 128 + c4);
            xv[0] = f.x; xv[1] = f.y; xv[2] = f.z; xv[3] = f.w;
            ushort4 u;
            u.x = f2bits(f.x); u.y = f2bits(f.y); u.z = f2bits(f.z); u.w = f2bits(f.w);
            *(ushort4*)(p.xb + (size_t)n * 128 + c4) = u;
        }
        float pr[8];
#pragma unroll
        for (int j = 0; j < 8; ++j) {
            const float* wv = wp1_s + j * 128 + c4;
            float t = 0.f;
            t = fmaf(xv[0], wv[0], t);
            t = fmaf(xv[1], wv[1], t);
            t = fmaf(xv[2], wv[2], t);
            t = fmaf(xv[3], wv[3], t);
            pr[j] = t;
        }
#pragma unroll
        for (int off = 1; off < 32; off <<= 1) {
#pragma unroll
            for (int j = 0; j < 8; ++j) pr[j] += __shfl_xor(pr[j], off, 32);
        }
        if (cl == 0) {
            *(float4*)(p.a1s + (size_t)n * 4) = make_float4(pr[0], pr[1], pr[2], pr[3]);
            *(float4*)(p.a1d + (size_t)n * 4) = make_float4(pr[4], pr[5], pr[6], pr[7]);
        }
    }
}

// ---------- per-edge eval helper ----------
__device__ __forceinline__ void edge_evals(const float* as_, int src, const float4& adv,
                                           float& s0, float& s1, float& s2, float& s3,
                                           float* slot) {
    float4 av = *(const float4*)(as_ + src * 4);
    float v0 = av.x + adv.x; v0 = v0 > 0.f ? v0 : NSL * v0; float e0 = __expf(v0);
    float v1 = av.y + adv.y; v1 = v1 > 0.f ? v1 : NSL * v1; float e1 = __expf(v1);
    float v2 = av.z + adv.z; v2 = v2 > 0.f ? v2 : NSL * v2; float e2 = __expf(v2);
    float v3 = av.w + adv.w; v3 = v3 > 0.f ? v3 : NSL * v3; float e3 = __expf(v3);
    s0 += e0; s1 += e1; s2 += e2; s3 += e3;
    *(float4*)slot = make_float4(e0, e1, e2, e3);
}

// ---------- K2: aggregate-first layer 1 (CIN=128); src offsets staged in LDS ----------
__global__ __launch_bounds__(256) void aggx128_k(MP p) {
    __shared__ float lal[4][CAP][4];
    __shared__ int   lsrc[4][CAP];
    const int lane = threadIdx.x & 63, seg = threadIdx.x >> 6;
    const int d = blockIdx.x * 4 + seg;              // 5000*4 = 20000 exact
    const int deg = min(p.cnt[d], CAP);
    const int base = d * CAP;
    const float4 adv = *(const float4*)(p.a1d + d * 4);
    const int src0 = (lane < deg) ? p.csr[base + lane] : 0;
    const int src1 = (64 + lane < deg) ? p.csr[base + 64 + lane] : 0;
    float s0 = 0, s1 = 0, s2 = 0, s3 = 0;
    if (lane < deg) {
        edge_evals(p.a1s, src0, adv, s0, s1, s2, s3, &lal[seg][lane][0]);
        lsrc[seg][lane] = src0 * 128;
    }
    if (64 + lane < deg) {
        edge_evals(p.a1s, src1, adv, s0, s1, s2, s3, &lal[seg][64 + lane][0]);
        lsrc[seg][64 + lane] = src1 * 128;
    }
    const int q = lane >> 4, c8 = (lane & 15) * 8;
    const float* lal_s = &lal[seg][0][0];
    const int* lsrc_s = &lsrc[seg][0];
    float a[8] = {0, 0, 0, 0, 0, 0, 0, 0};

    auto do_edge = [&](int idx) {
        float ev = lal_s[idx * 4 + q];               // broadcast within q-group
        int sof = lsrc_s[idx];                       // broadcast
        ushort8v xv = *(const ushort8v*)(p.xb + (size_t)sof + c8);
#pragma unroll
        for (int j = 0; j < 8; ++j) a[j] = fmaf(ev, bits2f(xv[j]), a[j]);
    };

    int e = 0;
    for (; e + 4 <= deg; e += 4) {
        do_edge(e); do_edge(e + 1); do_edge(e + 2); do_edge(e + 3);
    }
    for (; e < deg; ++e) do_edge(e);

#pragma unroll
    for (int off = 1; off < 64; off <<= 1) {
        s0 += __shfl_xor(s0, off, 64);
        s1 += __shfl_xor(s1, off, 64);
        s2 += __shfl_xor(s2, off, 64);
        s3 += __shfl_xor(s3, off, 64);
    }
    const float sq = (q == 0) ? s0 : (q == 1) ? s1 : (q == 2) ? s2 : s3;
    const float iq = 0.25f / (sq + 1e-16f);
    ushort8v pk;
#pragma unroll
    for (int j = 0; j < 8; ++j) pk[j] = f2bits(a[j] * iq);
    *(ushort8v*)(p.aggn + (size_t)d * 512 + q * 128 + c8) = pk;
}

// ---------- K4: aggregate-first layer 2 (CIN=64); src offsets staged in LDS ----------
__global__ __launch_bounds__(256) void aggx64_k(MP p) {
    __shared__ float lal[4][CAP][4];
    __shared__ int   lsrc[4][CAP];
    const int lane = threadIdx.x & 63, seg = threadIdx.x >> 6;
    const int d = blockIdx.x * 4 + seg;
    const int deg = min(p.cnt[d], CAP);
    const int base = d * CAP;
    const float4 adv = *(const float4*)(p.a2d + d * 4);
    const int src0 = (lane < deg) ? p.csr[base + lane] : 0;
    const int src1 = (64 + lane < deg) ? p.csr[base + 64 + lane] : 0;
    float s0 = 0, s1 = 0, s2 = 0, s3 = 0;
    if (lane < deg) {
        edge_evals(p.a2s, src0, adv, s0, s1, s2, s3, &lal[seg][lane][0]);
        lsrc[seg][lane] = src0 * 64;
    }
    if (64 + lane < deg) {
        edge_evals(p.a2s, src1, adv, s0, s1, s2, s3, &lal[seg][64 + lane][0]);
        lsrc[seg][64 + lane] = src1 * 64;
    }
    const int hl = lane >> 5, cl = lane & 31;
    const int q = cl >> 3, c8 = (cl & 7) * 8;
    const float* lal_s = &lal[seg][0][0];
    const int* lsrc_s = &lsrc[seg][0];
    float a[8] = {0, 0, 0, 0, 0, 0, 0, 0};

    auto do_edge = [&](int idx, bool valid) {
        float ev = valid ? lal_s[idx * 4 + q] : 0.0f;
        int off = valid ? lsrc_s[idx] : 0;
        ushort8v xv = *(const ushort8v*)(p.x1b + (size_t)off + c8);
#pragma unroll
        for (int j = 0; j < 8; ++j) a[j] = fmaf(ev, bits2f(xv[j]), a[j]);
    };

    int e = 0;
    for (; e + 8 <= deg; e += 8) {
        do_edge(e + hl, true);
        do_edge(e + 2 + hl, true);
        do_edge(e + 4 + hl, true);
        do_edge(e + 6 + hl, true);
    }
    for (; e < deg; e += 2) do_edge(e + hl, (e + hl) < deg);

#pragma unroll
    for (int off = 1; off < 64; off <<= 1) {
        s0 += __shfl_xor(s0, off, 64);
        s1 += __shfl_xor(s1, off, 64);
        s2 += __shfl_xor(s2, off, 64);
        s3 += __shfl_xor(s3, off, 64);
    }
#pragma unroll
    for (int j = 0; j < 8; ++j) a[j] += __shfl_xor(a[j], 32, 64);
    const float sq = (q == 0) ? s0 : (q == 1) ? s1 : (q == 2) ? s2 : s3;
    const float iq = 0.25f / (sq + 1e-16f);
    if (hl == 0) {
        ushort8v pk;
#pragma unroll
        for (int j = 0; j < 8; ++j) pk[j] = f2bits(a[j] * iq);
        *(ushort8v*)(p.aggn + (size_t)d * 256 + q * 64 + c8) = pk;
    }
}

// ---------- K3: layer-1 transform (MFMA) + fused layer-2 alphas ----------
__global__ __launch_bounds__(256) void cat1_k(MP p) {
    constexpr int K = 512, KC = 128, SW = KC + 8, NCH = K / KC;
    __shared__ ushortT wt_s[64 * SW];
    __shared__ ushortT xs[64 * SW];
    __shared__ float wp_s[512];
    const int bf = *p.fflag;
    const int lane = threadIdx.x & 63, w = threadIdx.x >> 6;
    const int ln = lane & 15, quad = lane >> 4;
    const int base = blockIdx.x * 64;                // grid 313
    float4v acc[4];
#pragma unroll
    for (int T = 0; T < 4; ++T) acc[T] = (float4v){0.f, 0.f, 0.f, 0.f};
    for (int i = threadIdx.x; i < 512; i += 256) wp_s[i] = p.wp2[i];
#pragma unroll
    for (int ch = 0; ch < NCH; ++ch) {
        for (int i = threadIdx.x; i < 64 * 16; i += 256) {
            int r = i >> 4, kc = (i & 15) * 8;
            *(short8*)(wt_s + r * SW + kc) =
                *(const short8*)(p.WT1c + (size_t)r * K + ch * KC + kc);
            int node = base + r;
            short8 v = {0, 0, 0, 0, 0, 0, 0, 0};
            if (node < Nn) v = *(const short8*)(p.aggn + (size_t)node * K + ch * KC + kc);
            *(short8*)(xs + r * SW + kc) = v;
        }
        __syncthreads();
#pragma unroll
        for (int ks = 0; ks < 4; ++ks) {
            const int kb = ks * 32 + quad * 8;
            const short8 bfr = *(const short8*)(xs + (w * 16 + ln) * SW + kb);
#pragma unroll
            for (int T = 0; T < 4; ++T) {
                const short8 afr = *(const short8*)(wt_s + (T * 16 + ln) * SW + kb);
                acc[T] = __builtin_amdgcn_mfma_f32_16x16x32_bf16(afr, bfr, acc[T], 0, 0, 0);
            }
        }
        __syncthreads();
    }
    const int node = base + w * 16 + ln;
    const bool live = node < Nn;
    ushortT* on = p.x1b + (size_t)node * 64;
    float pr[8];
#pragma unroll
    for (int j = 0; j < 8; ++j) pr[j] = 0.f;
#pragma unroll
    for (int T = 0; T < 4; ++T) {
        const int jl = T * 16 + quad * 4;
        ushort4 pk;
        float t0 = fmaxf(acc[T][0] + ldf(p.b1, jl + 0, bf), 0.f);
        float t1 = fmaxf(acc[T][1] + ldf(p.b1, jl + 1, bf), 0.f);
        float t2 = fmaxf(acc[T][2] + ldf(p.b1, jl + 2, bf), 0.f);
        float t3 = fmaxf(acc[T][3] + ldf(p.b1, jl + 3, bf), 0.f);
        pk.x = f2bits(t0); pk.y = f2bits(t1); pk.z = f2bits(t2); pk.w = f2bits(t3);
        if (live) *(ushort4*)(on + jl) = pk;
#pragma unroll
        for (int j = 0; j < 8; ++j) {
            pr[j] = fmaf(t0, wp_s[j * 64 + jl + 0], pr[j]);
            pr[j] = fmaf(t1, wp_s[j * 64 + jl + 1], pr[j]);
            pr[j] = fmaf(t2, wp_s[j * 64 + jl + 2], pr[j]);
            pr[j] = fmaf(t3, wp_s[j * 64 + jl + 3], pr[j]);
        }
    }
#pragma unroll
    for (int j = 0; j < 8; ++j) {
        pr[j] += __shfl_xor(pr[j], 16, 64);
        pr[j] += __shfl_xor(pr[j], 32, 64);
    }
    if (quad == 0 && live) {
        *(float4*)(p.a2s + (size_t)node * 4) = make_float4(pr[0], pr[1], pr[2], pr[3]);
        *(float4*)(p.a2d + (size_t)node * 4) = make_float4(pr[4], pr[5], pr[6], pr[7]);
    }
}

// ---------- K5: layer-2 transform + layer-3 GEMM fused per tile ----------
__global__ __launch_bounds__(256) void cat2s_k(MP p) {
    constexpr int K = 256, KC = 128, SW = KC + 8, NCH = K / KC, PAD = 36;
    __shared__ __align__(16) char pool[36864];
    ushortT* wt_s = (ushortT*)pool;                       // 17408 B (MFMA part)
    ushortT* xs   = (ushortT*)(pool + 17408);             // 17408 B (MFMA part)
    ushortT* x2t  = (ushortT*)pool;                       // 8192 B (reuse after MFMA)
    float*   xsh  = (float*)(pool + 8192);                // 9216 B
    const int bf = *p.fflag;
    const int lane = threadIdx.x & 63, w = threadIdx.x >> 6;
    const int ln = lane & 15, quad = lane >> 4;
    const int jc = threadIdx.x & 31, g = threadIdx.x >> 5;
    const int base = blockIdx.x * 64;                // grid 313
    float4v acc[4];
#pragma unroll
    for (int T = 0; T < 4; ++T) acc[T] = (float4v){0.f, 0.f, 0.f, 0.f};
#pragma unroll
    for (int ch = 0; ch < NCH; ++ch) {
        for (int i = threadIdx.x; i < 64 * 16; i += 256) {
            int r = i >> 4, kc = (i & 15) * 8;
            *(short8*)(wt_s + r * SW + kc) =
                *(const short8*)(p.WT2c + (size_t)r * K + ch * KC + kc);
            int node = base + r;
            short8 v = {0, 0, 0, 0, 0, 0, 0, 0};
            if (node < Nn) v = *(const short8*)(p.aggn + (size_t)node * K + ch * KC + kc);
            *(short8*)(xs + r * SW + kc) = v;
        }
        __syncthreads();
#pragma unroll
        for (int ks = 0; ks < 4; ++ks) {
            const int kb = ks * 32 + quad * 8;
            const short8 bfr = *(const short8*)(xs + (w * 16 + ln) * SW + kb);
#pragma unroll
            for (int T = 0; T < 4; ++T) {
                const short8 afr = *(const short8*)(wt_s + (T * 16 + ln) * SW + kb);
                acc[T] = __builtin_amdgcn_mfma_f32_16x16x32_bf16(afr, bfr, acc[T], 0, 0, 0);
            }
        }
        __syncthreads();
    }
    // epilogue: x2 = relu(acc + b2) -> LDS tile
#pragma unroll
    for (int T = 0; T < 4; ++T) {
        const int jl = T * 16 + quad * 4;
        ushort4 pk;
        pk.x = f2bits(fmaxf(acc[T][0] + ldf(p.b2, jl + 0, bf), 0.f));
        pk.y = f2bits(fmaxf(acc[T][1] + ldf(p.b2, jl + 1, bf), 0.f));
        pk.z = f2bits(fmaxf(acc[T][2] + ldf(p.b2, jl + 2, bf), 0.f));
        pk.w = f2bits(fmaxf(acc[T][3] + ldf(p.b2, jl + 3, bf), 0.f));
        *(ushort4*)(x2t + (w * 16 + ln) * 64 + jl) = pk;
    }
    __syncthreads();
    // layer-3 small GEMM on the tile (2 sub-blocks of 32 nodes)
    float avsr = ldf(p.as3, jc, bf), avdr = ldf(p.ad3, jc, bf);
#pragma unroll
    for (int sub = 0; sub < 2; ++sub) {
        for (int i = threadIdx.x; i < 32 * 64; i += 256) {
            int rr = i >> 6, kk = i & 63;
            xsh[kk * PAD + rr] = bits2f(x2t[(sub * 32 + rr) * 64 + kk]);
        }
        __syncthreads();
        float accs[4] = {};
        if (bf) {
            const __hip_bfloat16* Wb = (const __hip_bfloat16*)p.W3;
#pragma unroll 4
            for (int k = 0; k < 64; ++k) {
                float4 xv = *(const float4*)(xsh + k * PAD + g * 4);
                float wv = b2f(Wb[k * 32 + jc]);
                accs[0] = fmaf(xv.x, wv, accs[0]);
                accs[1] = fmaf(xv.y, wv, accs[1]);
                accs[2] = fmaf(xv.z, wv, accs[2]);
                accs[3] = fmaf(xv.w, wv, accs[3]);
            }
        } else {
            const float* Wf = (const float*)p.W3;
#pragma unroll 4
            for (int k = 0; k < 64; ++k) {
                float4 xv = *(const float4*)(xsh + k * PAD + g * 4);
                float wv = Wf[k * 32 + jc];
                accs[0] = fmaf(xv.x, wv, accs[0]);
                accs[1] = fmaf(xv.y, wv, accs[1]);
                accs[2] = fmaf(xv.z, wv, accs[2]);
                accs[3] = fmaf(xv.w, wv, accs[3]);
            }
        }
#pragma unroll
        for (int m = 0; m < 4; ++m) {
            int n = base + sub * 32 + g * 4 + m;
            if (n < Nn) {
                p.h3[(size_t)n * 32 + jc] = f2bits(accs[m]);
                float t1 = accs[m] * avsr;
                float t2 = accs[m] * avdr;
#pragma unroll
                for (int off = 16; off > 0; off >>= 1) {
                    t1 += __shfl_down(t1, off, 32);
                    t2 += __shfl_down(t2, off, 32);
                }
                if (jc == 0) { p.a3s[n] = t1; p.a3d[n] = t2; }
            }
        }
        __syncthreads();
    }
}

// ---------- K6: layer-3 aggregation fused with output heads ----------
__global__ __launch_bounds__(256) void aggr1f_k(MP p) {
    __shared__ float wm_s[1024], wv_s[1024];
    __shared__ float lal[8][CAP];
    __shared__ int   lof[8][CAP];
    const int bf = *p.fflag;
    for (int i = threadIdx.x; i < 1024; i += 256) {
        wm_s[i] = ldf(p.Wm, i, bf);
        wv_s[i] = ldf(p.Wv, i, bf);
    }
    __syncthreads();
    const int c = threadIdx.x & 31, seg = threadIdx.x >> 5;
    const int d = blockIdx.x * 8 + seg;              // 2500*8 = 20000 exact
    const int deg = min(p.cnt[d], CAP);
    const int base = d * CAP;
    const float advd = p.a3d[d];
    float s = 0;
    for (int i = c; i < deg; i += 32) {
        int src = p.csr[base + i];
        float v = p.a3s[src] + advd;
        v = v > 0.f ? v : NSL * v;
        float ev = __expf(v);
        s += ev;
        lal[seg][i] = ev;
        lof[seg][i] = src * 32;
    }
    float acc = 0.0f;
    int e = 0;
    for (; e + 4 <= deg; e += 4) {
        float ev0 = lal[seg][e], ev1 = lal[seg][e + 1];
        float ev2 = lal[seg][e + 2], ev3 = lal[seg][e + 3];
        int o0 = lof[seg][e], o1 = lof[seg][e + 1];
        int o2 = lof[seg][e + 2], o3 = lof[seg][e + 3];
        float h0 = bits2f(p.h3[o0 + c]), h1 = bits2f(p.h3[o1 + c]);
        float h2 = bits2f(p.h3[o2 + c]), h3v = bits2f(p.h3[o3 + c]);
        acc = fmaf(ev0, h0, acc);
        acc = fmaf(ev1, h1, acc);
        acc = fmaf(ev2, h2, acc);
        acc = fmaf(ev3, h3v, acc);
    }
    for (; e < deg; ++e) acc = fmaf(lal[seg][e], bits2f(p.h3[lof[seg][e] + c]), acc);
#pragma unroll
    for (int off = 1; off < 32; off <<= 1) s += __shfl_xor(s, off, 32);
    const float inv = 1.0f / (s + 1e-16f);
    const float z = inv * acc + ldf(p.b3, c, bf);
    stf(p.out, (size_t)2 * Nn * 32 + (size_t)d * 32 + c, z, bf);   // z
    float sm = ldf(p.bm, c, bf), sv = ldf(p.bv, c, bf);
#pragma unroll 8
    for (int k = 0; k < 32; ++k) {
        float zk = __shfl(z, k, 32);
        sm = fmaf(zk, wm_s[k * 32 + c], sm);
        sv = fmaf(zk, wv_s[k * 32 + c], sv);
    }
    float var = __expf(sv);
    var = fminf(fmaxf(var, 1e-8f), 100.0f);
    stf(p.out, (size_t)d * 32 + c, sm, bf);                        // z_mean
    stf(p.out, (size_t)Nn * 32 + (size_t)d * 32 + c, var, bf);     // z_var
}

// ---------- launch: memset + 6 dispatches ----------
extern "C" void kernel_launch(void* const* d_in, const int* in_sizes, int n_in,
                              void* d_out, int out_size, void* d_ws, size_t ws_size,
                              hipStream_t stream) {
    float* ws = (float*)d_ws;
    MP p;
    p.x   = d_in[0];  p.ei  = (const int*)d_in[1];
    p.W1  = d_in[2];  p.as1 = d_in[3];  p.ad1 = d_in[4];  p.b1 = d_in[5];
    p.W2  = d_in[6];  p.as2 = d_in[7];  p.ad2 = d_in[8];  p.b2 = d_in[9];
    p.W3  = d_in[10]; p.as3 = d_in[11]; p.ad3 = d_in[12]; p.b3 = d_in[13];
    p.Wm  = d_in[14]; p.bm  = d_in[15]; p.Wv  = d_in[16]; p.bv = d_in[17];
    p.aggn = (ushortT*)ws;                    // 20000*512 bf16
    p.xb   = (ushortT*)(ws + 5120000);        // 20000*128 bf16
    p.x1b  = (ushortT*)(ws + 6400000);        // 20000*64 bf16
    p.h3   = (ushortT*)(ws + 7040000);        // 20000*32 bf16
    p.a1s  = ws + 7360000;                    // 80,000
    p.a1d  = ws + 7440000;                    // 80,000
    p.a2s  = ws + 7520000;                    // 80,000
    p.a2d  = ws + 7600000;                    // 80,000
    p.a3s  = ws + 7680000;                    // 20,000
    p.a3d  = ws + 7700000;                    // 20,000
    p.WT1c = (ushortT*)(ws + 7720000);        // 64*512 bf16
    p.WT2c = (ushortT*)(ws + 7736384);        // 64*256 bf16
    p.wp2  = ws + 7745600;                    // 512
    p.cnt  = (int*)(ws + 7746112);            // 20,000
    p.csr  = (int*)(ws + 7766112);            // 2,560,000
    p.eflag = (int*)(ws + 10326112);
    p.fflag = (int*)(ws + 10326113);
    p.out  = d_out;

    hipMemsetAsync(p.cnt, 0, 20000 * sizeof(int), stream);
    prep_k<<<625, 256, 0, stream>>>(p);
    aggx128_k<<<5000, 256, 0, stream>>>(p);
    cat1_k<<<313, 256, 0, stream>>>(p);
    aggx64_k<<<5000, 256, 0, stream>>>(p);
    cat2s_k<<<313, 256, 0, stream>>>(p);
    aggr1f_k<<<2500, 256, 0, stream>>>(p);
}